// Round 1
// baseline (181.781 us; speedup 1.0000x reference)
//
#include <hip/hip_runtime.h>
#include <hip/hip_bf16.h>
#include <cstdint>

// Problem constants
#define BATCH 16
#define CDIM  128
#define EDIM  256
#define SDIM  16
#define LSEQ  4096           // 64*64
#define LN_EPS 1e-5f

// ws layout (float offsets)
#define WU_OFF    0                     // W_u    [16][128]  = Bm @ W_in
#define WC_OFF    2048                  // W_combo[128][128] = (W_out*D) @ W_in
#define WSC_OFF   18432                 // W_sc   [128][16]  = W_out @ Cm
#define BIASC_OFF 20480                 // bias_c [128] = b_out + (W_out*D)@b_in
#define BU_OFF    20608                 // bu     [16]  = Bm @ b_in
#define U_OFF     32768                 // u      [B][L][S] = 1048576 floats
#define ST_OFF    (32768 + 1048576)     // states [B][L][S] = 1048576 floats
// total = 2129920 floats = ~8.13 MB of ws

static __device__ __forceinline__ uint32_t umin_u32(uint32_t a, uint32_t b) {
    return a < b ? a : b;
}

#if __has_builtin(__builtin_amdgcn_rcpf)
  #define RCPF(x) __builtin_amdgcn_rcpf(x)
#else
  #define RCPF(x) (1.0f / (x))
#endif

// ---------------------------------------------------------------------------
// Kernel P: precompute combined weights (tiny)
// ---------------------------------------------------------------------------
__global__ __launch_bounds__(256) void prep_kernel(
    const float* __restrict__ A, const float* __restrict__ Bm,
    const float* __restrict__ Cm, const float* __restrict__ Dv,
    const float* __restrict__ W_in, const float* __restrict__ b_in,
    const float* __restrict__ W_out, const float* __restrict__ b_out,
    float* __restrict__ ws)
{
    int blk = blockIdx.x, tid = threadIdx.x;
    if (blk < 64) {                       // W_combo[c][ci]
        int idx = blk * 256 + tid;
        int c = idx >> 7, ci = idx & 127;
        float acc = 0.f;
        for (int e = 0; e < EDIM; ++e)
            acc += W_out[c * EDIM + e] * Dv[e] * W_in[e * CDIM + ci];
        ws[WC_OFF + idx] = acc;
    } else if (blk < 72) {                // W_u[s][ci]
        int idx = (blk - 64) * 256 + tid;
        int s = idx >> 7, ci = idx & 127;
        float acc = 0.f;
        for (int e = 0; e < EDIM; ++e)
            acc += Bm[s * EDIM + e] * W_in[e * CDIM + ci];
        ws[WU_OFF + idx] = acc;
    } else if (blk < 80) {                // W_sc[c][s]
        int idx = (blk - 72) * 256 + tid;
        int c = idx >> 4, s = idx & 15;
        float acc = 0.f;
        for (int e = 0; e < EDIM; ++e)
            acc += W_out[c * EDIM + e] * Cm[e * SDIM + s];
        ws[WSC_OFF + idx] = acc;
    } else {                              // biases
        if (tid < 128) {
            float acc = b_out[tid];
            for (int e = 0; e < EDIM; ++e)
                acc += W_out[tid * EDIM + e] * Dv[e] * b_in[e];
            ws[BIASC_OFF + tid] = acc;
        } else if (tid < 144) {
            int s = tid - 128;
            float acc = 0.f;
            for (int e = 0; e < EDIM; ++e)
                acc += Bm[s * EDIM + e] * b_in[e];
            ws[BU_OFF + s] = acc;
        }
    }
}

// ---------------------------------------------------------------------------
// Kernel 1: LayerNorm + u = hn @ W_u^T + bu      (64 positions per block)
// ---------------------------------------------------------------------------
__global__ __launch_bounds__(256) void ln_u_kernel(
    const float* __restrict__ x, const float* __restrict__ gamma,
    const float* __restrict__ beta, float* __restrict__ ws)
{
    __shared__ __align__(16) float xs[128][64];   // x tile -> hn in place
    __shared__ __align__(16) float wu[128][16];   // W_u transposed: wu[ci][s]
    __shared__ float red1[4][64], red2[4][64];
    __shared__ float mu_s[64], rs_s[64];

    int tid = threadIdx.x;
    int b   = blockIdx.x >> 6;
    int hw0 = (blockIdx.x & 63) << 6;
    const float* xb = x + (size_t)b * CDIM * LSEQ + hw0;

    // stage x tile (coalesced 256B rows)
    #pragma unroll 4
    for (int it = 0; it < 32; ++it) {
        int idx = it * 256 + tid;
        int c = idx >> 6, p = idx & 63;
        xs[c][p] = xb[(size_t)c * LSEQ + p];
    }
    // stage W_u (transpose into LDS)
    for (int it = 0; it < 8; ++it) {
        int idx = it * 256 + tid;
        int s = idx >> 7, ci = idx & 127;
        wu[ci][s] = ws[WU_OFF + idx];
    }
    __syncthreads();

    // LN stats: 4 threads per position
    {
        int q = tid >> 6, p = tid & 63;
        float sm = 0.f, sq = 0.f;
        #pragma unroll 8
        for (int i = 0; i < 32; ++i) {
            float v = xs[q * 32 + i][p];
            sm += v; sq += v * v;
        }
        red1[q][p] = sm; red2[q][p] = sq;
        __syncthreads();
        if (q == 0) {
            float s1 = red1[0][p] + red1[1][p] + red1[2][p] + red1[3][p];
            float s2 = red2[0][p] + red2[1][p] + red2[2][p] + red2[3][p];
            float mu = s1 * (1.f / 128.f);
            float var = s2 * (1.f / 128.f) - mu * mu;
            mu_s[p] = mu;
            rs_s[p] = rsqrtf(var + LN_EPS);
        }
        __syncthreads();
    }
    // normalize in place
    #pragma unroll 4
    for (int it = 0; it < 32; ++it) {
        int idx = it * 256 + tid;
        int c = idx >> 6, p = idx & 63;
        xs[c][p] = (xs[c][p] - mu_s[p]) * rs_s[p] * gamma[c] + beta[c];
    }
    __syncthreads();

    // u GEMM: thread (g,s): s = tid&15, 4 positions g*4+j
    {
        int s = tid & 15, g = tid >> 4;
        float bu = ws[BU_OFF + s];
        float a0 = bu, a1 = bu, a2 = bu, a3 = bu;
        #pragma unroll 8
        for (int ci = 0; ci < 128; ++ci) {
            float w = wu[ci][s];
            a0 = fmaf(w, xs[ci][g * 4 + 0], a0);
            a1 = fmaf(w, xs[ci][g * 4 + 1], a1);
            a2 = fmaf(w, xs[ci][g * 4 + 2], a2);
            a3 = fmaf(w, xs[ci][g * 4 + 3], a3);
        }
        float* u = ws + U_OFF + (size_t)b * (LSEQ * SDIM) + (size_t)hw0 * SDIM;
        u[(g * 4 + 0) * SDIM + s] = a0;
        u[(g * 4 + 1) * SDIM + s] = a1;
        u[(g * 4 + 2) * SDIM + s] = a2;
        u[(g * 4 + 3) * SDIM + s] = a3;
    }
}

// ---------------------------------------------------------------------------
// Kernel 2: chunked tanh scan.
// 128 chunks of 32 steps, 64-step zero-init halo (contraction: err < 1e-6).
// One 16-lane group per (chunk,batch) recurrence; DPP row_ror for the dot.
// ---------------------------------------------------------------------------
#define SCAN_CHUNK 32
#define SCAN_HALO  64

#define ROT_I(VAL, K) __builtin_amdgcn_mov_dpp((VAL), 0x120 + (K), 0xF, 0xF, true)
#define REP15(M) M(1) M(2) M(3) M(4) M(5) M(6) M(7) M(8) M(9) M(10) M(11) M(12) M(13) M(14) M(15)

__global__ __launch_bounds__(64) void scan_kernel(
    const float* __restrict__ Amat, float* __restrict__ ws)
{
    int lane = threadIdx.x;
    int s = lane & 15;
    int g = lane >> 4;
    int rec = blockIdx.x * 4 + g;          // 2048 recs
    int b = rec & 15;
    int chunk = rec >> 4;                  // uniform across the wave
    int t0 = chunk * SCAN_CHUNK;
    int tstart = t0 - SCAN_HALO; if (tstart < 0) tstart = 0;
    int tend = t0 + SCAN_CHUNK;

    // per-lane coefficients Ak[k] = A[s][sigma_k(s)], sigma via the SAME dpp
    float Ak[16];
    Ak[0] = Amat[s * 16 + s];
    {
        int pk;
        #define PERMLOAD(K) pk = ROT_I(s, K); Ak[K] = Amat[s * 16 + pk];
        REP15(PERMLOAD)
        #undef PERMLOAD
    }

    const float* up = ws + U_OFF;
    float* stp = ws + ST_OFF;
    const uint32_t umax = (uint32_t)(BATCH * LSEQ * SDIM - 1);
    uint32_t base = (uint32_t)b * (LSEQ * SDIM) + (uint32_t)tstart * SDIM + (uint32_t)s;

    // 8-deep prefetch ring (statically indexed)
    float ub[8];
    #pragma unroll
    for (int j = 0; j < 8; ++j) ub[j] = up[umin_u32(base + j * 16u, umax)];
    uint32_t loff = base + 128u;
    uint32_t soff = base;

    float st = 0.f;
    for (int t = tstart; t < tend; t += 8) {
        bool dostore = (t >= t0);          // uniform (t0-tstart multiple of 8)
        #pragma unroll
        for (int j = 0; j < 8; ++j) {
            float u_t = ub[j];
            ub[j] = up[umin_u32(loff, umax)];   // prefetch t+8
            loff += 16u;
            float a0 = fmaf(Ak[0], st, u_t);
            float a1 = 0.f, a2 = 0.f, a3 = 0.f;
            #define ROTFMA(K) { float r_ = __int_as_float(ROT_I(__float_as_int(st), K)); \
                if ((K & 3) == 0)      a0 = fmaf(Ak[K], r_, a0); \
                else if ((K & 3) == 1) a1 = fmaf(Ak[K], r_, a1); \
                else if ((K & 3) == 2) a2 = fmaf(Ak[K], r_, a2); \
                else                   a3 = fmaf(Ak[K], r_, a3); }
            REP15(ROTFMA)
            #undef ROTFMA
            float X = (a0 + a2) + (a1 + a3);
            float ex = __expf(X + X);                 // e^{2X}
            st = fmaf(-2.f, RCPF(ex + 1.f), 1.f);     // tanh(X)
            if (dostore) stp[soff] = st;
            soff += 16u;
        }
    }
}

// ---------------------------------------------------------------------------
// Kernel 3: recompute LN, out = hn@W_combo^T + states@W_sc^T + bias_c + x
// 64 positions per block; out tile transposed through LDS for coalesced store.
// ---------------------------------------------------------------------------
__global__ __launch_bounds__(256) void out_kernel(
    const float* __restrict__ x, const float* __restrict__ gamma,
    const float* __restrict__ beta, float* __restrict__ out,
    const float* __restrict__ ws)
{
    __shared__ __align__(16) float hs[128][64];    // x -> hn -> out tile
    __shared__ __align__(16) float wct[32][132];   // W_combo tile, transposed, padded
    __shared__ __align__(16) float wsc[16][128];   // W_sc transposed [s][c]
    __shared__ __align__(16) float stl[16][64];    // states [s][pos]
    __shared__ float red1[4][64], red2[4][64];
    __shared__ float mu_s[64], rs_s[64];

    int tid = threadIdx.x;
    int b   = blockIdx.x >> 6;
    int hw0 = (blockIdx.x & 63) << 6;
    const float* xb  = x   + (size_t)b * CDIM * LSEQ + hw0;
    float*       ob  = out + (size_t)b * CDIM * LSEQ + hw0;

    // stage x
    #pragma unroll 4
    for (int it = 0; it < 32; ++it) {
        int idx = it * 256 + tid;
        int c = idx >> 6, p = idx & 63;
        hs[c][p] = xb[(size_t)c * LSEQ + p];
    }
    // stage W_sc transposed
    for (int it = 0; it < 8; ++it) {
        int idx = it * 256 + tid;
        int c = idx >> 4, s = idx & 15;
        wsc[s][c] = ws[WSC_OFF + idx];
    }
    // stage states tile transposed
    {
        const float* stg = ws + ST_OFF + (size_t)b * (LSEQ * SDIM) + (size_t)hw0 * SDIM;
        for (int it = 0; it < 4; ++it) {
            int idx = it * 256 + tid;
            int p = idx >> 4, s = idx & 15;
            stl[s][p] = stg[idx];
        }
    }
    __syncthreads();

    // LN stats
    {
        int q = tid >> 6, p = tid & 63;
        float sm = 0.f, sq = 0.f;
        #pragma unroll 8
        for (int i = 0; i < 32; ++i) {
            float v = hs[q * 32 + i][p];
            sm += v; sq += v * v;
        }
        red1[q][p] = sm; red2[q][p] = sq;
        __syncthreads();
        if (q == 0) {
            float s1 = red1[0][p] + red1[1][p] + red1[2][p] + red1[3][p];
            float s2 = red2[0][p] + red2[1][p] + red2[2][p] + red2[3][p];
            float mu = s1 * (1.f / 128.f);
            float var = s2 * (1.f / 128.f) - mu * mu;
            mu_s[p] = mu;
            rs_s[p] = rsqrtf(var + LN_EPS);
        }
        __syncthreads();
    }
    #pragma unroll 4
    for (int it = 0; it < 32; ++it) {
        int idx = it * 256 + tid;
        int c = idx >> 6, p = idx & 63;
        hs[c][p] = (hs[c][p] - mu_s[p]) * rs_s[p] * gamma[c] + beta[c];
    }
    __syncthreads();

    // main GEMM: thread -> 4 c_out x 8 pos
    int pt = tid & 7, ct = tid >> 3;
    int c0 = ct * 4, p0 = pt * 8;
    float acc[4][8];
    #pragma unroll
    for (int i = 0; i < 4; ++i)
        #pragma unroll
        for (int j = 0; j < 8; ++j) acc[i][j] = 0.f;

    for (int tile = 0; tile < 4; ++tile) {
        // stage W_combo tile transposed: wct[cl][c]
        for (int it = 0; it < 16; ++it) {
            int idx = it * 256 + tid;
            int c = idx >> 5, cl = idx & 31;
            wct[cl][c] = ws[WC_OFF + c * 128 + tile * 32 + cl];
        }
        __syncthreads();
        #pragma unroll 4
        for (int cl = 0; cl < 32; ++cl) {
            float4 w4 = *(const float4*)&wct[cl][c0];
            float4 ha = *(const float4*)&hs[tile * 32 + cl][p0];
            float4 hb = *(const float4*)&hs[tile * 32 + cl][p0 + 4];
            const float wr[4] = {w4.x, w4.y, w4.z, w4.w};
            const float hr[8] = {ha.x, ha.y, ha.z, ha.w, hb.x, hb.y, hb.z, hb.w};
            #pragma unroll
            for (int i = 0; i < 4; ++i)
                #pragma unroll
                for (int j = 0; j < 8; ++j)
                    acc[i][j] = fmaf(wr[i], hr[j], acc[i][j]);
        }
        __syncthreads();
    }

    // states contribution
    #pragma unroll
    for (int s = 0; s < 16; ++s) {
        float4 w4 = *(const float4*)&wsc[s][c0];
        float4 ha = *(const float4*)&stl[s][p0];
        float4 hb = *(const float4*)&stl[s][p0 + 4];
        const float wr[4] = {w4.x, w4.y, w4.z, w4.w};
        const float hr[8] = {ha.x, ha.y, ha.z, ha.w, hb.x, hb.y, hb.z, hb.w};
        #pragma unroll
        for (int i = 0; i < 4; ++i)
            #pragma unroll
            for (int j = 0; j < 8; ++j)
                acc[i][j] = fmaf(wr[i], hr[j], acc[i][j]);
    }
    // bias
    #pragma unroll
    for (int i = 0; i < 4; ++i) {
        float bc = ws[BIASC_OFF + c0 + i];
        #pragma unroll
        for (int j = 0; j < 8; ++j) acc[i][j] += bc;
    }

    __syncthreads();     // all hs reads done (tile loop barriers) — safe to overwrite
    #pragma unroll
    for (int i = 0; i < 4; ++i)
        #pragma unroll
        for (int j = 0; j < 8; ++j)
            hs[c0 + i][p0 + j] = acc[i][j];
    __syncthreads();

    // coalesced store + residual (x re-read hits L2)
    #pragma unroll 4
    for (int it = 0; it < 32; ++it) {
        int idx = it * 256 + tid;
        int c = idx >> 6, p = idx & 63;
        ob[(size_t)c * LSEQ + p] = hs[c][p] + xb[(size_t)c * LSEQ + p];
    }
}

// ---------------------------------------------------------------------------
extern "C" void kernel_launch(void* const* d_in, const int* in_sizes, int n_in,
                              void* d_out, int out_size, void* d_ws, size_t ws_size,
                              hipStream_t stream)
{
    const float* x     = (const float*)d_in[0];
    const float* A     = (const float*)d_in[1];
    const float* Bm    = (const float*)d_in[2];
    const float* Cm    = (const float*)d_in[3];
    const float* Dv    = (const float*)d_in[4];
    const float* W_in  = (const float*)d_in[5];
    const float* b_in  = (const float*)d_in[6];
    const float* W_out = (const float*)d_in[7];
    const float* b_out = (const float*)d_in[8];
    const float* gamma = (const float*)d_in[9];
    const float* beta  = (const float*)d_in[10];
    float* ws  = (float*)d_ws;
    float* out = (float*)d_out;

    prep_kernel<<<dim3(81),   dim3(256), 0, stream>>>(A, Bm, Cm, Dv, W_in, b_in, W_out, b_out, ws);
    ln_u_kernel<<<dim3(1024), dim3(256), 0, stream>>>(x, gamma, beta, ws);
    scan_kernel<<<dim3(512),  dim3(64),  0, stream>>>(A, ws);
    out_kernel<<<dim3(1024),  dim3(256), 0, stream>>>(x, gamma, beta, out, ws);
}

// Round 2
// 161.219 us; speedup vs baseline: 1.1275x; 1.1275x over previous
//
#include <hip/hip_runtime.h>
#include <cstdint>

#define BATCH 16
#define CDIM  128
#define EDIM  256
#define SDIM  16
#define LSEQ  4096
#define LN_EPS 1e-5f

typedef __attribute__((ext_vector_type(8))) short short8;
typedef __attribute__((ext_vector_type(4))) float f32x4;
typedef __attribute__((ext_vector_type(4))) unsigned int u32x4;

// ---- ws layout (32-bit word offsets) ----
#define WC32   0            // fp32 W_combo [128][128]
#define WU32   16384        // fp32 W_u     [16][128]
#define WSC32  18432        // fp32 W_sc    [128][16]
#define BIASC  20480        // fp32 bias_c  [128]
#define BU     20608        // fp32 bu      [16]
#define WCF    20736        // K3 A-frags: plane(2) x kt(5) x mf(8) x lane(64) x 4 words
#define WUF    41216        // K1 A-frags: plane(2) x kt(4) x lane(64) x 4 words
#define U_OFF  65536        // u      [B][L][S] fp32
#define ST_OFF (U_OFF + BATCH*LSEQ*SDIM)   // states [B][L][S] fp32

static __device__ __forceinline__ uint32_t umin_u32(uint32_t a, uint32_t b) { return a < b ? a : b; }

static __device__ __forceinline__ unsigned short f2bf(float f) {
    uint32_t u = __float_as_uint(f);
    uint32_t r = u + 0x7fffu + ((u >> 16) & 1u);   // RTNE
    return (unsigned short)(r >> 16);
}
static __device__ __forceinline__ float bf2f(unsigned short h) {
    return __uint_as_float(((uint32_t)h) << 16);
}
static __device__ __forceinline__ uint32_t pack_split(float v) {
    unsigned short h = f2bf(v);
    unsigned short l = f2bf(v - bf2f(h));
    return (uint32_t)h | ((uint32_t)l << 16);      // low16 = hi plane, high16 = lo plane
}
static __device__ __forceinline__ uint32_t pack2bf(float a, float b) {
    return (uint32_t)f2bf(a) | ((uint32_t)f2bf(b) << 16);
}

union U4S8 { u32x4 u; short8 s; };

static __device__ __forceinline__ uint32_t permb(uint32_t a, uint32_t b, uint32_t sel) {
    return __builtin_amdgcn_perm(a, b, sel);
}

// Extract hi-plane and lo-plane B-frags (8 bf16 each) from 8 packed words at
// swizzled LDS row. cb = k-chunk base (multiple of 4 words), sw = (p&7)<<2.
static __device__ __forceinline__ void load_bfrag(const uint32_t* row, int cb, int sw,
                                                  short8& bh, short8& bl) {
    u32x4 A = *reinterpret_cast<const u32x4*>(&row[(cb) ^ sw]);
    u32x4 B = *reinterpret_cast<const u32x4*>(&row[(cb + 4) ^ sw]);
    U4S8 h, l;
    h.u[0] = permb(A[1], A[0], 0x05040100u);
    h.u[1] = permb(A[3], A[2], 0x05040100u);
    h.u[2] = permb(B[1], B[0], 0x05040100u);
    h.u[3] = permb(B[3], B[2], 0x05040100u);
    l.u[0] = permb(A[1], A[0], 0x07060302u);
    l.u[1] = permb(A[3], A[2], 0x07060302u);
    l.u[2] = permb(B[1], B[0], 0x07060302u);
    l.u[3] = permb(B[3], B[2], 0x07060302u);
    bh = h.s; bl = l.s;
}

#define MFMA(acc, a, b) acc = __builtin_amdgcn_mfma_f32_16x16x32_bf16((a), (b), (acc), 0, 0, 0)

// ---------------------------------------------------------------------------
// prep1: fp32 combined weights.
//   W_combo = (W_out * diag(D)) @ W_in   [128][128]
//   W_u     = Bm @ W_in                  [16][128]
//   W_sc    = W_out @ Cm                 [128][16]
//   bias_c  = b_out + (W_out*D) @ b_in ;  bu = Bm @ b_in
// ---------------------------------------------------------------------------
__global__ __launch_bounds__(256) void prep1_kernel(
    const float* __restrict__ Bm, const float* __restrict__ Cm,
    const float* __restrict__ Dv, const float* __restrict__ W_in,
    const float* __restrict__ b_in, const float* __restrict__ W_out,
    const float* __restrict__ b_out, float* __restrict__ ws)
{
    int blk = blockIdx.x, tid = threadIdx.x;
    if (blk < 64) {
        int idx = blk * 256 + tid;
        int c = idx >> 7, ci = idx & 127;
        float acc = 0.f;
        #pragma unroll 8
        for (int e = 0; e < EDIM; ++e)
            acc += W_out[c * EDIM + e] * Dv[e] * W_in[e * CDIM + ci];
        ws[WC32 + idx] = acc;
    } else if (blk < 72) {
        int idx = (blk - 64) * 256 + tid;
        int s = idx >> 7, ci = idx & 127;
        float acc = 0.f;
        #pragma unroll 8
        for (int e = 0; e < EDIM; ++e)
            acc += Bm[s * EDIM + e] * W_in[e * CDIM + ci];
        ws[WU32 + idx] = acc;
    } else if (blk < 80) {
        int idx = (blk - 72) * 256 + tid;
        int c = idx >> 4, s = idx & 15;
        float acc = 0.f;
        #pragma unroll 8
        for (int e = 0; e < EDIM; ++e)
            acc += W_out[c * EDIM + e] * Cm[e * SDIM + s];
        ws[WSC32 + idx] = acc;
    } else {
        if (tid < 128) {
            float acc = b_out[tid];
            #pragma unroll 8
            for (int e = 0; e < EDIM; ++e)
                acc += W_out[tid * EDIM + e] * Dv[e] * b_in[e];
            ws[BIASC + tid] = acc;
        } else if (tid < 144) {
            int s = tid - 128;
            float acc = 0.f;
            #pragma unroll 8
            for (int e = 0; e < EDIM; ++e)
                acc += Bm[s * EDIM + e] * b_in[e];
            ws[BU + s] = acc;
        }
    }
}

// ---------------------------------------------------------------------------
// prep2: split W into hi/lo bf16 and lay out as MFMA A-fragments.
// A-frag element: lane l holds A[row = mf*16 + (l&15)][k = kt*32 + (l>>4)*8 + j].
// Word w packs (j=2*j2, j=2*j2+1):  w = ((kt*MF + mf)*64 + l)*4 + j2.
// K3: MF=8, kt 0..4 (kt 4 = W_sc rows, k 128..159, zero-padded past s=16).
// K1: MF=1, kt 0..3 (W_u).
// ---------------------------------------------------------------------------
__global__ __launch_bounds__(256) void prep2_kernel(float* __restrict__ ws)
{
    uint32_t* wsu = (uint32_t*)ws;
    int blk = blockIdx.x, tid = threadIdx.x;
    if (blk < 80) {
        int wg = blk * 256 + tid;            // 0..20479
        int plane = wg / 10240;
        int w = wg % 10240;
        int j2 = w & 3;
        int l  = (w >> 2) & 63;
        int mf = (w >> 8) & 7;
        int kt = w >> 11;                    // 0..4
        int row = mf * 16 + (l & 15);
        int kb = kt * 32 + ((l >> 4) << 3) + j2 * 2;
        float v0, v1;
        if (kt < 4) {
            v0 = ws[WC32 + row * 128 + kb];
            v1 = ws[WC32 + row * 128 + kb + 1];
        } else {
            int s0 = kb - 128, s1 = kb - 127;
            v0 = (s0 < 16) ? ws[WSC32 + row * 16 + s0] : 0.f;
            v1 = (s1 < 16) ? ws[WSC32 + row * 16 + s1] : 0.f;
        }
        unsigned short h0 = f2bf(v0), h1 = f2bf(v1);
        uint32_t word;
        if (plane == 0) word = (uint32_t)h0 | ((uint32_t)h1 << 16);
        else {
            unsigned short l0 = f2bf(v0 - bf2f(h0));
            unsigned short l1 = f2bf(v1 - bf2f(h1));
            word = (uint32_t)l0 | ((uint32_t)l1 << 16);
        }
        wsu[WCF + wg] = word;
    } else if (blk < 88) {
        int idx = (blk - 80) * 256 + tid;    // 0..2047
        int plane = idx >> 10;
        int w = idx & 1023;
        int j2 = w & 3;
        int l  = (w >> 2) & 63;
        int kt = (w >> 8) & 3;
        int row = l & 15;
        int kb = kt * 32 + ((l >> 4) << 3) + j2 * 2;
        float v0 = ws[WU32 + row * 128 + kb];
        float v1 = ws[WU32 + row * 128 + kb + 1];
        unsigned short h0 = f2bf(v0), h1 = f2bf(v1);
        uint32_t word;
        if (plane == 0) word = (uint32_t)h0 | ((uint32_t)h1 << 16);
        else {
            unsigned short l0 = f2bf(v0 - bf2f(h0));
            unsigned short l1 = f2bf(v1 - bf2f(h1));
            word = (uint32_t)l0 | ((uint32_t)l1 << 16);
        }
        wsu[WUF + idx] = word;
    }
}

// ---------------------------------------------------------------------------
// K1: LN + u = hn @ W_u^T + bu  via split-bf16 MFMA.  128 positions / block.
// LDS tile xs: fp32 x (transposed [p][c], XOR-swizzled) -> packed hi|lo in place.
// ---------------------------------------------------------------------------
__global__ __launch_bounds__(256, 2) void ln_u_kernel(
    const float* __restrict__ x, const float* __restrict__ gamma,
    const float* __restrict__ beta, float* __restrict__ ws)
{
    __shared__ uint32_t xs[16384];           // 64 KB: [p][c] words, swizzle ^((p&7)<<2)
    __shared__ float ul[2560];               // u frags transposed [p][20-pad]
    __shared__ float gb[256];
    __shared__ float pr1[2][128], pr2[2][128];
    __shared__ float mu_s[128], rs_s[128];

    int tid = threadIdx.x;
    int lane = tid & 63, wv = tid >> 6;
    int b  = blockIdx.x >> 5;
    int P0 = (blockIdx.x & 31) << 7;
    const float* xb = x + ((size_t)b * CDIM) * LSEQ + P0;
    const uint32_t* wsu = (const uint32_t*)ws;

    // A-frags (same for all waves): auh/aul[kt]
    short8 auh[4], aul[4];
    #pragma unroll
    for (int kt = 0; kt < 4; ++kt) {
        U4S8 t;
        t.u = *reinterpret_cast<const u32x4*>(&wsu[WUF + kt * 256 + lane * 4]);
        auh[kt] = t.s;
        t.u = *reinterpret_cast<const u32x4*>(&wsu[WUF + 1024 + kt * 256 + lane * 4]);
        aul[kt] = t.s;
    }
    if (tid < 128) { gb[tid] = gamma[tid]; gb[128 + tid] = beta[tid]; }

    // stage x: transpose [c][p] global -> [p][c] LDS (swizzled)
    #pragma unroll
    for (int it = 0; it < 16; ++it) {
        int idx = it * 256 + tid;
        int c = idx >> 5, p4 = (idx & 31) << 2;
        f32x4 v = *reinterpret_cast<const f32x4*>(xb + (size_t)c * LSEQ + p4);
        #pragma unroll
        for (int j = 0; j < 4; ++j) {
            int p = p4 + j;
            xs[p * 128 + (c ^ ((p & 7) << 2))] = __float_as_uint(v[j]);
        }
    }
    __syncthreads();

    // LN stats
    {
        int p = tid & 127, half = tid >> 7, c0 = half * 64, sw = (p & 7) << 2;
        const uint32_t* row = xs + p * 128;
        float sm = 0.f, sq = 0.f;
        #pragma unroll
        for (int it = 0; it < 16; ++it) {
            u32x4 w = *reinterpret_cast<const u32x4*>(&row[(c0 + it * 4) ^ sw]);
            #pragma unroll
            for (int j = 0; j < 4; ++j) { float v = __uint_as_float(w[j]); sm += v; sq += v * v; }
        }
        pr1[half][p] = sm; pr2[half][p] = sq;
    }
    __syncthreads();
    if (tid < 128) {
        float s1 = pr1[0][tid] + pr1[1][tid];
        float s2 = pr2[0][tid] + pr2[1][tid];
        float mu = s1 * (1.f / 128.f);
        float var = s2 * (1.f / 128.f) - mu * mu;
        mu_s[tid] = mu; rs_s[tid] = rsqrtf(var + LN_EPS);
    }
    __syncthreads();

    // normalize + split-pack in place
    {
        int p = tid & 127, half = tid >> 7, c0 = half * 64, sw = (p & 7) << 2;
        uint32_t* row = xs + p * 128;
        float mu = mu_s[p], rs = rs_s[p];
        #pragma unroll
        for (int it = 0; it < 16; ++it) {
            int cb = c0 + it * 4;
            u32x4 w = *reinterpret_cast<u32x4*>(&row[cb ^ sw]);
            #pragma unroll
            for (int j = 0; j < 4; ++j) {
                int c = cb + j;
                float val = (__uint_as_float(w[j]) - mu) * rs * gb[c] + gb[128 + c];
                w[j] = pack_split(val);
            }
            *reinterpret_cast<u32x4*>(&row[cb ^ sw]) = w;
        }
    }
    __syncthreads();

    // MFMA: wave wv handles nf = wv*2 + {0,1}
    #pragma unroll
    for (int nfi = 0; nfi < 2; ++nfi) {
        int nf = wv * 2 + nfi;
        int p = nf * 16 + (lane & 15);
        const uint32_t* row = xs + p * 128;
        int sw = (p & 7) << 2;
        f32x4 acc = {0.f, 0.f, 0.f, 0.f};
        #pragma unroll
        for (int kt = 0; kt < 4; ++kt) {
            short8 bh, bl;
            load_bfrag(row, kt * 32 + ((lane >> 4) << 3), sw, bh, bl);
            MFMA(acc, auh[kt], bh);
            MFMA(acc, auh[kt], bl);
            MFMA(acc, aul[kt], bh);
        }
        #pragma unroll
        for (int j = 0; j < 4; ++j)
            ul[p * 20 + ((lane >> 4) << 2) + j] = acc[j];
    }
    __syncthreads();

    // store u (+bu), coalesced float4
    {
        float* uptr = ws + U_OFF + (size_t)b * (LSEQ * SDIM);
        int s4 = (tid & 3) << 2;
        f32x4 buv = *reinterpret_cast<const f32x4*>(ws + BU + s4);
        #pragma unroll
        for (int it = 0; it < 2; ++it) {
            int p = it * 64 + (tid >> 2);
            f32x4 vv;
            #pragma unroll
            for (int j = 0; j < 4; ++j) vv[j] = ul[p * 20 + s4 + j];
            *reinterpret_cast<f32x4*>(uptr + ((size_t)(P0 + p)) * SDIM + s4) = vv + buv;
        }
    }
}

// ---------------------------------------------------------------------------
// K2: chunked tanh scan (unchanged from round 1, new ws offsets).
// ---------------------------------------------------------------------------
#define SCAN_CHUNK 32
#define SCAN_HALO  64
#define ROT_I(VAL, K) __builtin_amdgcn_mov_dpp((VAL), 0x120 + (K), 0xF, 0xF, true)
#define REP15(M) M(1) M(2) M(3) M(4) M(5) M(6) M(7) M(8) M(9) M(10) M(11) M(12) M(13) M(14) M(15)

#if __has_builtin(__builtin_amdgcn_rcpf)
  #define RCPF(x) __builtin_amdgcn_rcpf(x)
#else
  #define RCPF(x) (1.0f / (x))
#endif

__global__ __launch_bounds__(64) void scan_kernel(
    const float* __restrict__ Amat, float* __restrict__ ws)
{
    int lane = threadIdx.x;
    int s = lane & 15;
    int g = lane >> 4;
    int rec = blockIdx.x * 4 + g;
    int b = rec & 15;
    int chunk = rec >> 4;
    int t0 = chunk * SCAN_CHUNK;
    int tstart = t0 - SCAN_HALO; if (tstart < 0) tstart = 0;
    int tend = t0 + SCAN_CHUNK;

    float Ak[16];
    Ak[0] = Amat[s * 16 + s];
    {
        int pk;
        #define PERMLOAD(K) pk = ROT_I(s, K); Ak[K] = Amat[s * 16 + pk];
        REP15(PERMLOAD)
        #undef PERMLOAD
    }

    const float* up = ws + U_OFF;
    float* stp = ws + ST_OFF;
    const uint32_t umax = (uint32_t)(BATCH * LSEQ * SDIM - 1);
    uint32_t base = (uint32_t)b * (LSEQ * SDIM) + (uint32_t)tstart * SDIM + (uint32_t)s;

    float ub[8];
    #pragma unroll
    for (int j = 0; j < 8; ++j) ub[j] = up[umin_u32(base + j * 16u, umax)];
    uint32_t loff = base + 128u;
    uint32_t soff = base;

    float st = 0.f;
    for (int t = tstart; t < tend; t += 8) {
        bool dostore = (t >= t0);
        #pragma unroll
        for (int j = 0; j < 8; ++j) {
            float u_t = ub[j];
            ub[j] = up[umin_u32(loff, umax)];
            loff += 16u;
            float a0 = fmaf(Ak[0], st, u_t);
            float a1 = 0.f, a2 = 0.f, a3 = 0.f;
            #define ROTFMA(K) { float r_ = __int_as_float(ROT_I(__float_as_int(st), K)); \
                if ((K & 3) == 0)      a0 = fmaf(Ak[K], r_, a0); \
                else if ((K & 3) == 1) a1 = fmaf(Ak[K], r_, a1); \
                else if ((K & 3) == 2) a2 = fmaf(Ak[K], r_, a2); \
                else                   a3 = fmaf(Ak[K], r_, a3); }
            REP15(ROTFMA)
            #undef ROTFMA
            float X = (a0 + a2) + (a1 + a3);
            float ex = __expf(X + X);
            st = fmaf(-2.f, RCPF(ex + 1.f), 1.f);
            if (dostore) stp[soff] = st;
            soff += 16u;
        }
    }
}

// ---------------------------------------------------------------------------
// K3: LN recompute + out = W_combo@hn + W_sc@states + bias + x  (split-bf16 MFMA)
// 128 positions x 128 c_out per block.  States folded in as K-tile 4.
// ---------------------------------------------------------------------------
__global__ __launch_bounds__(256, 2) void out_kernel(
    const float* __restrict__ x, const float* __restrict__ gamma,
    const float* __restrict__ beta, float* __restrict__ out,
    const float* __restrict__ ws)
{
    __shared__ uint32_t xs[16384];                 // 64 KB
    __shared__ unsigned short stl[4096];           // 8 KB: states bf16 [p][32], s>=16 zero
    __shared__ float gb[256];
    __shared__ float pr1[2][128], pr2[2][128];
    __shared__ float mu_s[128], rs_s[128];

    int tid = threadIdx.x;
    int lane = tid & 63, wv = tid >> 6;
    int b  = blockIdx.x >> 5;
    int P0 = (blockIdx.x & 31) << 7;
    const float* xb = x + ((size_t)b * CDIM) * LSEQ + P0;
    const uint32_t* wsu = (const uint32_t*)ws;

    if (tid < 128) { gb[tid] = gamma[tid]; gb[128 + tid] = beta[tid]; }

    // stage states tile -> bf16 [p][32] (zero-padded upper 16)
    {
        int p = tid >> 1, s8 = (tid & 1) << 3;
        const float* sp = ws + ST_OFF + ((size_t)(b * LSEQ + P0 + p)) * SDIM + s8;
        f32x4 a0 = *reinterpret_cast<const f32x4*>(sp);
        f32x4 a1 = *reinterpret_cast<const f32x4*>(sp + 4);
        u32x4 w;
        w[0] = pack2bf(a0[0], a0[1]); w[1] = pack2bf(a0[2], a0[3]);
        w[2] = pack2bf(a1[0], a1[1]); w[3] = pack2bf(a1[2], a1[3]);
        *reinterpret_cast<u32x4*>(&stl[p * 32 + s8]) = w;
        u32x4 z = {0u, 0u, 0u, 0u};
        *reinterpret_cast<u32x4*>(&stl[p * 32 + 16 + s8]) = z;
    }

    // stage x
    #pragma unroll
    for (int it = 0; it < 16; ++it) {
        int idx = it * 256 + tid;
        int c = idx >> 5, p4 = (idx & 31) << 2;
        f32x4 v = *reinterpret_cast<const f32x4*>(xb + (size_t)c * LSEQ + p4);
        #pragma unroll
        for (int j = 0; j < 4; ++j) {
            int p = p4 + j;
            xs[p * 128 + (c ^ ((p & 7) << 2))] = __float_as_uint(v[j]);
        }
    }
    __syncthreads();

    // LN stats
    {
        int p = tid & 127, half = tid >> 7, c0 = half * 64, sw = (p & 7) << 2;
        const uint32_t* row = xs + p * 128;
        float sm = 0.f, sq = 0.f;
        #pragma unroll
        for (int it = 0; it < 16; ++it) {
            u32x4 w = *reinterpret_cast<const u32x4*>(&row[(c0 + it * 4) ^ sw]);
            #pragma unroll
            for (int j = 0; j < 4; ++j) { float v = __uint_as_float(w[j]); sm += v; sq += v * v; }
        }
        pr1[half][p] = sm; pr2[half][p] = sq;
    }
    __syncthreads();
    if (tid < 128) {
        float s1 = pr1[0][tid] + pr1[1][tid];
        float s2 = pr2[0][tid] + pr2[1][tid];
        float mu = s1 * (1.f / 128.f);
        float var = s2 * (1.f / 128.f) - mu * mu;
        mu_s[tid] = mu; rs_s[tid] = rsqrtf(var + LN_EPS);
    }
    __syncthreads();

    // normalize + split-pack in place
    {
        int p = tid & 127, half = tid >> 7, c0 = half * 64, sw = (p & 7) << 2;
        uint32_t* row = xs + p * 128;
        float mu = mu_s[p], rs = rs_s[p];
        #pragma unroll
        for (int it = 0; it < 16; ++it) {
            int cb = c0 + it * 4;
            u32x4 w = *reinterpret_cast<u32x4*>(&row[cb ^ sw]);
            #pragma unroll
            for (int j = 0; j < 4; ++j) {
                int c = cb + j;
                float val = (__uint_as_float(w[j]) - mu) * rs * gb[c] + gb[128 + c];
                w[j] = pack_split(val);
            }
            *reinterpret_cast<u32x4*>(&row[cb ^ sw]) = w;
        }
    }
    __syncthreads();

    // MFMA: wave wv -> rows [wv*32, wv*32+32), all 8 N-frags.
    f32x4 acc[2][8];
    #pragma unroll
    for (int m = 0; m < 2; ++m)
        #pragma unroll
        for (int nf = 0; nf < 8; ++nf) { f32x4 z = {0.f,0.f,0.f,0.f}; acc[m][nf] = z; }

    #pragma unroll
    for (int kt = 0; kt < 4; ++kt) {
        short8 ah[2], al[2];
        #pragma unroll
        for (int m = 0; m < 2; ++m) {
            int mfg = wv * 2 + m;
            U4S8 t;
            t.u = *reinterpret_cast<const u32x4*>(&wsu[WCF + (kt * 8 + mfg) * 256 + lane * 4]);
            ah[m] = t.s;
            t.u = *reinterpret_cast<const u32x4*>(&wsu[WCF + 10240 + (kt * 8 + mfg) * 256 + lane * 4]);
            al[m] = t.s;
        }
        #pragma unroll
        for (int nf = 0; nf < 8; ++nf) {
            int p = nf * 16 + (lane & 15);
            const uint32_t* row = xs + p * 128;
            short8 bh, bl;
            load_bfrag(row, kt * 32 + ((lane >> 4) << 3), (p & 7) << 2, bh, bl);
            #pragma unroll
            for (int m = 0; m < 2; ++m) {
                MFMA(acc[m][nf], ah[m], bh);
                MFMA(acc[m][nf], ah[m], bl);
                MFMA(acc[m][nf], al[m], bh);
            }
        }
    }
    // states K-tile (kt = 4): B from stl (upper half reads the zero region)
    {
        short8 ah[2], al[2];
        #pragma unroll
        for (int m = 0; m < 2; ++m) {
            int mfg = wv * 2 + m;
            U4S8 t;
            t.u = *reinterpret_cast<const u32x4*>(&wsu[WCF + (4 * 8 + mfg) * 256 + lane * 4]);
            ah[m] = t.s;
            t.u = *reinterpret_cast<const u32x4*>(&wsu[WCF + 10240 + (4 * 8 + mfg) * 256 + lane * 4]);
            al[m] = t.s;
        }
        int grp = lane >> 4;
        #pragma unroll
        for (int nf = 0; nf < 8; ++nf) {
            int p = nf * 16 + (lane & 15);
            U4S8 t;
            t.u = *reinterpret_cast<const u32x4*>(&stl[p * 32 + grp * 8]);
            short8 bs = t.s;
            #pragma unroll
            for (int m = 0; m < 2; ++m) {
                MFMA(acc[m][nf], ah[m], bs);
                MFMA(acc[m][nf], al[m], bs);
            }
        }
    }

    // epilogue: + bias + residual, direct stores (16-lane 64B segments)
    {
        float bc[2][4];
        #pragma unroll
        for (int m = 0; m < 2; ++m)
            #pragma unroll
            for (int j = 0; j < 4; ++j)
                bc[m][j] = ws[BIASC + wv * 32 + m * 16 + ((lane >> 4) << 2) + j];
        #pragma unroll
        for (int m = 0; m < 2; ++m) {
            #pragma unroll
            for (int j = 0; j < 4; ++j) {
                int c = wv * 32 + m * 16 + ((lane >> 4) << 2) + j;
                const size_t rowa = ((size_t)(b * CDIM + c)) * LSEQ + P0;
                #pragma unroll
                for (int nf = 0; nf < 8; ++nf) {
                    int p = nf * 16 + (lane & 15);
                    out[rowa + p] = acc[m][nf][j] + bc[m][j] + x[rowa + p];
                }
            }
        }
    }
}

// ---------------------------------------------------------------------------
extern "C" void kernel_launch(void* const* d_in, const int* in_sizes, int n_in,
                              void* d_out, int out_size, void* d_ws, size_t ws_size,
                              hipStream_t stream)
{
    const float* x     = (const float*)d_in[0];
    const float* A     = (const float*)d_in[1];
    const float* Bm    = (const float*)d_in[2];
    const float* Cm    = (const float*)d_in[3];
    const float* Dv    = (const float*)d_in[4];
    const float* W_in  = (const float*)d_in[5];
    const float* b_in  = (const float*)d_in[6];
    const float* W_out = (const float*)d_in[7];
    const float* b_out = (const float*)d_in[8];
    const float* gamma = (const float*)d_in[9];
    const float* beta  = (const float*)d_in[10];
    float* ws  = (float*)d_ws;
    float* out = (float*)d_out;

    prep1_kernel<<<dim3(81),  dim3(256), 0, stream>>>(Bm, Cm, Dv, W_in, b_in, W_out, b_out, ws);
    prep2_kernel<<<dim3(88),  dim3(256), 0, stream>>>(ws);
    ln_u_kernel <<<dim3(512), dim3(256), 0, stream>>>(x, gamma, beta, ws);
    scan_kernel <<<dim3(512), dim3(64),  0, stream>>>(A, ws);
    out_kernel  <<<dim3(512), dim3(256), 0, stream>>>(x, gamma, beta, out, ws);
}

// Round 3
// 159.227 us; speedup vs baseline: 1.1416x; 1.0125x over previous
//
#include <hip/hip_runtime.h>
#include <cstdint>

#define BATCH 16
#define CDIM  128
#define EDIM  256
#define SDIM  16
#define LSEQ  4096
#define LN_EPS 1e-5f

typedef __attribute__((ext_vector_type(8))) short short8;
typedef __attribute__((ext_vector_type(4))) float f32x4;
typedef __attribute__((ext_vector_type(4))) unsigned int u32x4;

// ---- ws layout (32-bit word offsets) ----
#define BIASC  20480        // fp32 bias_c [128]
#define BU     20608        // fp32 bu     [16]
#define WCF    20736        // K3 A-frags: plane(2) x kt(5) x mf(8) x lane(64) x 4 words
#define WUF    41216        // K1 A-frags: plane(2) x kt(4) x lane(64) x 4 words
#define U_OFF  65536        // u      [B][L][S] fp32
#define ST_OFF (U_OFF + BATCH*LSEQ*SDIM)   // states [B][L][S] fp32

static __device__ __forceinline__ uint32_t umin_u32(uint32_t a, uint32_t b) { return a < b ? a : b; }

static __device__ __forceinline__ unsigned short f2bf(float f) {
    uint32_t u = __float_as_uint(f);
    uint32_t r = u + 0x7fffu + ((u >> 16) & 1u);   // RTNE
    return (unsigned short)(r >> 16);
}
static __device__ __forceinline__ float bf2f(unsigned short h) {
    return __uint_as_float(((uint32_t)h) << 16);
}
// truncation split: hi = trunc16(v), lo = RTNE(v - hi). hi+lo ≈ v to ~2^-17 rel.
static __device__ __forceinline__ uint32_t pack_split_trunc(float v) {
    uint32_t u = __float_as_uint(v);
    float hi_f = __uint_as_float(u & 0xffff0000u);
    unsigned short lo = f2bf(v - hi_f);
    return (u >> 16) | ((uint32_t)lo << 16);       // low16 = hi plane, high16 = lo plane
}
static __device__ __forceinline__ uint32_t pack2bf(float a, float b) {
    return (uint32_t)f2bf(a) | ((uint32_t)f2bf(b) << 16);
}

union U4S8 { u32x4 u; short8 s; };

static __device__ __forceinline__ uint32_t permb(uint32_t a, uint32_t b, uint32_t sel) {
    return __builtin_amdgcn_perm(a, b, sel);
}

// Extract hi-plane and lo-plane B-frags (8 bf16 each) from 8 packed words at
// swizzled LDS row. cb = k-chunk base (multiple of 4 words), sw = (p&7)<<2.
static __device__ __forceinline__ void load_bfrag(const uint32_t* row, int cb, int sw,
                                                  short8& bh, short8& bl) {
    u32x4 A = *reinterpret_cast<const u32x4*>(&row[(cb) ^ sw]);
    u32x4 B = *reinterpret_cast<const u32x4*>(&row[(cb + 4) ^ sw]);
    U4S8 h, l;
    h.u[0] = permb(A[1], A[0], 0x05040100u);
    h.u[1] = permb(A[3], A[2], 0x05040100u);
    h.u[2] = permb(B[1], B[0], 0x05040100u);
    h.u[3] = permb(B[3], B[2], 0x05040100u);
    l.u[0] = permb(A[1], A[0], 0x07060302u);
    l.u[1] = permb(A[3], A[2], 0x07060302u);
    l.u[2] = permb(B[1], B[0], 0x07060302u);
    l.u[3] = permb(B[3], B[2], 0x07060302u);
    bh = h.s; bl = l.s;
}

#define MFMA(acc, a, b) acc = __builtin_amdgcn_mfma_f32_16x16x32_bf16((a), (b), (acc), 0, 0, 0)

// ---------------------------------------------------------------------------
// prep: compute split-bf16 MFMA A-fragments directly from the e-dots.
//   frag value v(row,k): k<128 -> sum_e W_out[row,e]*D[e]*W_in[e,k]
//                        k>=128 -> s=k-128<16 ? sum_e W_out[row,e]*Cm[e,s] : 0
//   W_u frag: v = sum_e Bm[row,e]*W_in[e,k]
//   biases: bias_c = b_out + (W_out*D)@b_in ;  bu = Bm @ b_in
// ---------------------------------------------------------------------------
__global__ __launch_bounds__(256) void prep_kernel(
    const float* __restrict__ Bm, const float* __restrict__ Cm,
    const float* __restrict__ Dv, const float* __restrict__ W_in,
    const float* __restrict__ b_in, const float* __restrict__ W_out,
    const float* __restrict__ b_out, float* __restrict__ ws)
{
    uint32_t* wsu = (uint32_t*)ws;
    int blk = blockIdx.x, tid = threadIdx.x;
    if (blk < 40) {                       // K3 frag word-pairs, widx in [0,10240)
        int widx = blk * 256 + tid;
        int j2 = widx & 3;
        int l  = (widx >> 2) & 63;
        int mf = (widx >> 8) & 7;
        int kt = widx >> 11;              // 0..4
        int row = mf * 16 + (l & 15);
        int k0 = kt * 32 + ((l >> 4) << 3) + j2 * 2;
        float v0 = 0.f, v1 = 0.f;
        if (kt < 4) {
            #pragma unroll 4
            for (int e = 0; e < EDIM; ++e) {
                float wd = W_out[row * EDIM + e] * Dv[e];
                v0 = fmaf(wd, W_in[e * CDIM + k0], v0);
                v1 = fmaf(wd, W_in[e * CDIM + k0 + 1], v1);
            }
        } else {
            int s0 = k0 - 128;
            if (s0 < 16) {
                #pragma unroll 4
                for (int e = 0; e < EDIM; ++e) {
                    float wo = W_out[row * EDIM + e];
                    v0 = fmaf(wo, Cm[e * SDIM + s0], v0);
                    v1 = fmaf(wo, Cm[e * SDIM + s0 + 1], v1);
                }
            }
        }
        unsigned short h0 = f2bf(v0), h1 = f2bf(v1);
        unsigned short l0 = f2bf(v0 - bf2f(h0));
        unsigned short l1 = f2bf(v1 - bf2f(h1));
        wsu[WCF + widx]         = (uint32_t)h0 | ((uint32_t)h1 << 16);
        wsu[WCF + 10240 + widx] = (uint32_t)l0 | ((uint32_t)l1 << 16);
    } else if (blk < 44) {                // K1 (W_u) frag word-pairs, widx in [0,1024)
        int widx = (blk - 40) * 256 + tid;
        int j2 = widx & 3;
        int l  = (widx >> 2) & 63;
        int kt = (widx >> 8) & 3;
        int row = l & 15;
        int k0 = kt * 32 + ((l >> 4) << 3) + j2 * 2;
        float v0 = 0.f, v1 = 0.f;
        #pragma unroll 4
        for (int e = 0; e < EDIM; ++e) {
            float bm = Bm[row * EDIM + e];
            v0 = fmaf(bm, W_in[e * CDIM + k0], v0);
            v1 = fmaf(bm, W_in[e * CDIM + k0 + 1], v1);
        }
        unsigned short h0 = f2bf(v0), h1 = f2bf(v1);
        unsigned short l0 = f2bf(v0 - bf2f(h0));
        unsigned short l1 = f2bf(v1 - bf2f(h1));
        wsu[WUF + widx]        = (uint32_t)h0 | ((uint32_t)h1 << 16);
        wsu[WUF + 1024 + widx] = (uint32_t)l0 | ((uint32_t)l1 << 16);
    } else {                              // biases
        if (tid < 128) {
            float acc = b_out[tid];
            #pragma unroll 4
            for (int e = 0; e < EDIM; ++e)
                acc += W_out[tid * EDIM + e] * Dv[e] * b_in[e];
            ws[BIASC + tid] = acc;
        } else if (tid < 144) {
            int s = tid - 128;
            float acc = 0.f;
            #pragma unroll 4
            for (int e = 0; e < EDIM; ++e)
                acc += Bm[s * EDIM + e] * b_in[e];
            ws[BU + s] = acc;
        }
    }
}

// ---------------------------------------------------------------------------
// K1: LN + u = hn @ W_u^T + bu  via split-bf16 MFMA.  128 positions / block.
// LN stats folded into the staging loop (register partials + shfl_xor(32)).
// ---------------------------------------------------------------------------
__global__ __launch_bounds__(256, 2) void ln_u_kernel(
    const float* __restrict__ x, const float* __restrict__ gamma,
    const float* __restrict__ beta, float* __restrict__ ws)
{
    __shared__ uint32_t xs[16384];           // 64 KB: [p][c] words, swizzle ^((p&7)<<2)
    __shared__ float scratch[2560];          // pr1[4][128] @0, pr2 @512 -> later ul[p*20+..]
    __shared__ float mu_s[128], rs_s[128];
    __shared__ float gb[256];

    int tid = threadIdx.x;
    int lane = tid & 63, wv = tid >> 6;
    int b  = blockIdx.x >> 5;
    int P0 = (blockIdx.x & 31) << 7;
    const float* xb = x + ((size_t)b * CDIM) * LSEQ + P0;
    const uint32_t* wsu = (const uint32_t*)ws;

    // A-frags (same for all waves)
    short8 auh[4], aul[4];
    #pragma unroll
    for (int kt = 0; kt < 4; ++kt) {
        U4S8 t;
        t.u = *reinterpret_cast<const u32x4*>(&wsu[WUF + kt * 256 + lane * 4]);
        auh[kt] = t.s;
        t.u = *reinterpret_cast<const u32x4*>(&wsu[WUF + 1024 + kt * 256 + lane * 4]);
        aul[kt] = t.s;
    }
    if (tid < 128) { gb[tid] = gamma[tid]; gb[128 + tid] = beta[tid]; }

    // stage x ([c][p] global -> [p][c] LDS swizzled) with folded LN partials
    int p4 = (tid & 31) << 2;
    {
        float sm0=0.f,sm1=0.f,sm2=0.f,sm3=0.f, sq0=0.f,sq1=0.f,sq2=0.f,sq3=0.f;
        #pragma unroll
        for (int it = 0; it < 16; ++it) {
            int c = it * 8 + (tid >> 5);
            f32x4 v = *reinterpret_cast<const f32x4*>(xb + (size_t)c * LSEQ + p4);
            sm0 += v[0]; sq0 += v[0]*v[0];
            sm1 += v[1]; sq1 += v[1]*v[1];
            sm2 += v[2]; sq2 += v[2]*v[2];
            sm3 += v[3]; sq3 += v[3]*v[3];
            #pragma unroll
            for (int j = 0; j < 4; ++j) {
                int p = p4 + j;
                xs[p * 128 + (c ^ ((p & 7) << 2))] = __float_as_uint(v[j]);
            }
        }
        sm0 += __shfl_xor(sm0, 32); sq0 += __shfl_xor(sq0, 32);
        sm1 += __shfl_xor(sm1, 32); sq1 += __shfl_xor(sq1, 32);
        sm2 += __shfl_xor(sm2, 32); sq2 += __shfl_xor(sq2, 32);
        sm3 += __shfl_xor(sm3, 32); sq3 += __shfl_xor(sq3, 32);
        if ((tid & 32) == 0) {
            float* pr1 = scratch, * pr2 = scratch + 512;
            pr1[wv * 128 + p4 + 0] = sm0; pr2[wv * 128 + p4 + 0] = sq0;
            pr1[wv * 128 + p4 + 1] = sm1; pr2[wv * 128 + p4 + 1] = sq1;
            pr1[wv * 128 + p4 + 2] = sm2; pr2[wv * 128 + p4 + 2] = sq2;
            pr1[wv * 128 + p4 + 3] = sm3; pr2[wv * 128 + p4 + 3] = sq3;
        }
    }
    __syncthreads();
    if (tid < 128) {
        const float* pr1 = scratch, * pr2 = scratch + 512;
        float s1 = pr1[tid] + pr1[128 + tid] + pr1[256 + tid] + pr1[384 + tid];
        float s2 = pr2[tid] + pr2[128 + tid] + pr2[256 + tid] + pr2[384 + tid];
        float mu = s1 * (1.f / 128.f);
        float var = s2 * (1.f / 128.f) - mu * mu;
        mu_s[tid] = mu; rs_s[tid] = rsqrtf(var + LN_EPS);
    }
    __syncthreads();

    // normalize + split-pack in place (truncation hi)
    {
        int p = tid & 127, half = tid >> 7, c0 = half * 64, sw = (p & 7) << 2;
        uint32_t* row = xs + p * 128;
        float mu = mu_s[p], rs = rs_s[p];
        #pragma unroll
        for (int it = 0; it < 16; ++it) {
            int cb = c0 + it * 4;
            u32x4 w = *reinterpret_cast<u32x4*>(&row[cb ^ sw]);
            #pragma unroll
            for (int j = 0; j < 4; ++j) {
                int c = cb + j;
                float val = (__uint_as_float(w[j]) - mu) * rs * gb[c] + gb[128 + c];
                w[j] = pack_split_trunc(val);
            }
            *reinterpret_cast<u32x4*>(&row[cb ^ sw]) = w;
        }
    }
    __syncthreads();

    // MFMA: wave wv handles nf = wv*2 + {0,1}; results to scratch (as ul[p*20+..])
    float* ul = scratch;
    #pragma unroll
    for (int nfi = 0; nfi < 2; ++nfi) {
        int nf = wv * 2 + nfi;
        int p = nf * 16 + (lane & 15);
        const uint32_t* row = xs + p * 128;
        int sw = (p & 7) << 2;
        f32x4 acc = {0.f, 0.f, 0.f, 0.f};
        #pragma unroll
        for (int kt = 0; kt < 4; ++kt) {
            short8 bh, bl;
            load_bfrag(row, kt * 32 + ((lane >> 4) << 3), sw, bh, bl);
            MFMA(acc, auh[kt], bh);
            MFMA(acc, auh[kt], bl);
            MFMA(acc, aul[kt], bh);
        }
        #pragma unroll
        for (int j = 0; j < 4; ++j)
            ul[p * 20 + ((lane >> 4) << 2) + j] = acc[j];
    }
    __syncthreads();

    // store u (+bu), coalesced float4
    {
        float* uptr = ws + U_OFF + (size_t)b * (LSEQ * SDIM);
        int s4 = (tid & 3) << 2;
        f32x4 buv = *reinterpret_cast<const f32x4*>(ws + BU + s4);
        #pragma unroll
        for (int it = 0; it < 2; ++it) {
            int p = it * 64 + (tid >> 2);
            f32x4 vv;
            #pragma unroll
            for (int j = 0; j < 4; ++j) vv[j] = ul[p * 20 + s4 + j];
            *reinterpret_cast<f32x4*>(uptr + ((size_t)(P0 + p)) * SDIM + s4) = vv + buv;
        }
    }
}

// ---------------------------------------------------------------------------
// K2: chunked tanh scan.  chunk 32, halo 64, 16-deep prefetch ring.
// ---------------------------------------------------------------------------
#define ROT_I(VAL, K) __builtin_amdgcn_mov_dpp((VAL), 0x120 + (K), 0xF, 0xF, true)
#define REP15(M) M(1) M(2) M(3) M(4) M(5) M(6) M(7) M(8) M(9) M(10) M(11) M(12) M(13) M(14) M(15)

#if __has_builtin(__builtin_amdgcn_rcpf)
  #define RCPF(x) __builtin_amdgcn_rcpf(x)
#else
  #define RCPF(x) (1.0f / (x))
#endif

__global__ __launch_bounds__(64) void scan_kernel(
    const float* __restrict__ Amat, float* __restrict__ ws)
{
    int lane = threadIdx.x;
    int s = lane & 15;
    int g = lane >> 4;
    int rec = blockIdx.x * 4 + g;
    int b = rec & 15;
    int chunk = rec >> 4;
    int t0 = chunk * 32;
    int tstart = t0 - 64; if (tstart < 0) tstart = 0;
    int tend = t0 + 32;

    float Ak[16];
    Ak[0] = Amat[s * 16 + s];
    {
        int pk;
        #define PERMLOAD(K) pk = ROT_I(s, K); Ak[K] = Amat[s * 16 + pk];
        REP15(PERMLOAD)
        #undef PERMLOAD
    }

    const float* up = ws + U_OFF;
    float* stp = ws + ST_OFF;
    const uint32_t umax = (uint32_t)(BATCH * LSEQ * SDIM - 1);
    uint32_t base = (uint32_t)b * (LSEQ * SDIM) + (uint32_t)tstart * SDIM + (uint32_t)s;

    float ub[16];
    #pragma unroll
    for (int j = 0; j < 16; ++j) ub[j] = up[umin_u32(base + j * 16u, umax)];
    uint32_t loff = base + 256u;
    uint32_t soff = base;

    float st = 0.f;
    for (int t = tstart; t < tend; t += 16) {
        bool dostore = (t >= t0);          // uniform: block boundaries are x16
        #pragma unroll
        for (int j = 0; j < 16; ++j) {
            float u_t = ub[j];
            ub[j] = up[umin_u32(loff, umax)];   // prefetch t+16
            loff += 16u;
            float a0 = fmaf(Ak[0], st, u_t);
            float a1 = 0.f, a2 = 0.f, a3 = 0.f;
            #define ROTFMA(K) { float r_ = __int_as_float(ROT_I(__float_as_int(st), K)); \
                if ((K & 3) == 0)      a0 = fmaf(Ak[K], r_, a0); \
                else if ((K & 3) == 1) a1 = fmaf(Ak[K], r_, a1); \
                else if ((K & 3) == 2) a2 = fmaf(Ak[K], r_, a2); \
                else                   a3 = fmaf(Ak[K], r_, a3); }
            REP15(ROTFMA)
            #undef ROTFMA
            float X = (a0 + a2) + (a1 + a3);
            float ex = __expf(X + X);
            st = fmaf(-2.f, RCPF(ex + 1.f), 1.f);
            if (dostore) stp[soff] = st;
            soff += 16u;
        }
    }
}

// ---------------------------------------------------------------------------
// K3: LN recompute + out = W_combo@hn + W_sc@states + bias + x.
// 2x2 wave tiling (wm: rows, wn: positions); states folded as K-tile 4 (1 term).
// ---------------------------------------------------------------------------
__global__ __launch_bounds__(256, 2) void out_kernel(
    const float* __restrict__ x, const float* __restrict__ gamma,
    const float* __restrict__ beta, float* __restrict__ out,
    const float* __restrict__ ws)
{
    __shared__ uint32_t xs[16384];                 // 64 KB
    __shared__ unsigned short stl[4096];           // 8 KB: states bf16 [p][32], s>=16 zero
    __shared__ float pr1[4][128], pr2[4][128];
    __shared__ float mu_s[128], rs_s[128];
    __shared__ float gb[256];

    int tid = threadIdx.x;
    int lane = tid & 63, wv = tid >> 6;
    int b  = blockIdx.x >> 5;
    int P0 = (blockIdx.x & 31) << 7;
    const float* xb = x   + ((size_t)b * CDIM) * LSEQ + P0;
    float*       ob = out + ((size_t)b * CDIM) * LSEQ + P0;
    const uint32_t* wsu = (const uint32_t*)ws;

    if (tid < 128) { gb[tid] = gamma[tid]; gb[128 + tid] = beta[tid]; }

    // stage states tile -> bf16 [p][32] (zero-padded upper 16)
    {
        int p = tid >> 1, s8 = (tid & 1) << 3;
        const float* sp = ws + ST_OFF + ((size_t)(b * LSEQ + P0 + p)) * SDIM + s8;
        f32x4 a0 = *reinterpret_cast<const f32x4*>(sp);
        f32x4 a1 = *reinterpret_cast<const f32x4*>(sp + 4);
        u32x4 w;
        w[0] = pack2bf(a0[0], a0[1]); w[1] = pack2bf(a0[2], a0[3]);
        w[2] = pack2bf(a1[0], a1[1]); w[3] = pack2bf(a1[2], a1[3]);
        *reinterpret_cast<u32x4*>(&stl[p * 32 + s8]) = w;
        u32x4 z = {0u, 0u, 0u, 0u};
        *reinterpret_cast<u32x4*>(&stl[p * 32 + 16 + s8]) = z;
    }

    // stage x with folded LN partials
    int p4 = (tid & 31) << 2;
    {
        float sm0=0.f,sm1=0.f,sm2=0.f,sm3=0.f, sq0=0.f,sq1=0.f,sq2=0.f,sq3=0.f;
        #pragma unroll
        for (int it = 0; it < 16; ++it) {
            int c = it * 8 + (tid >> 5);
            f32x4 v = *reinterpret_cast<const f32x4*>(xb + (size_t)c * LSEQ + p4);
            sm0 += v[0]; sq0 += v[0]*v[0];
            sm1 += v[1]; sq1 += v[1]*v[1];
            sm2 += v[2]; sq2 += v[2]*v[2];
            sm3 += v[3]; sq3 += v[3]*v[3];
            #pragma unroll
            for (int j = 0; j < 4; ++j) {
                int p = p4 + j;
                xs[p * 128 + (c ^ ((p & 7) << 2))] = __float_as_uint(v[j]);
            }
        }
        sm0 += __shfl_xor(sm0, 32); sq0 += __shfl_xor(sq0, 32);
        sm1 += __shfl_xor(sm1, 32); sq1 += __shfl_xor(sq1, 32);
        sm2 += __shfl_xor(sm2, 32); sq2 += __shfl_xor(sq2, 32);
        sm3 += __shfl_xor(sm3, 32); sq3 += __shfl_xor(sq3, 32);
        if ((tid & 32) == 0) {
            pr1[wv][p4 + 0] = sm0; pr2[wv][p4 + 0] = sq0;
            pr1[wv][p4 + 1] = sm1; pr2[wv][p4 + 1] = sq1;
            pr1[wv][p4 + 2] = sm2; pr2[wv][p4 + 2] = sq2;
            pr1[wv][p4 + 3] = sm3; pr2[wv][p4 + 3] = sq3;
        }
    }
    __syncthreads();
    if (tid < 128) {
        float s1 = pr1[0][tid] + pr1[1][tid] + pr1[2][tid] + pr1[3][tid];
        float s2 = pr2[0][tid] + pr2[1][tid] + pr2[2][tid] + pr2[3][tid];
        float mu = s1 * (1.f / 128.f);
        float var = s2 * (1.f / 128.f) - mu * mu;
        mu_s[tid] = mu; rs_s[tid] = rsqrtf(var + LN_EPS);
    }
    __syncthreads();

    // normalize + split-pack in place (truncation hi)
    {
        int p = tid & 127, half = tid >> 7, c0 = half * 64, sw = (p & 7) << 2;
        uint32_t* row = xs + p * 128;
        float mu = mu_s[p], rs = rs_s[p];
        #pragma unroll
        for (int it = 0; it < 16; ++it) {
            int cb = c0 + it * 4;
            u32x4 w = *reinterpret_cast<u32x4*>(&row[cb ^ sw]);
            #pragma unroll
            for (int j = 0; j < 4; ++j) {
                int c = cb + j;
                float val = (__uint_as_float(w[j]) - mu) * rs * gb[c] + gb[128 + c];
                w[j] = pack_split_trunc(val);
            }
            *reinterpret_cast<u32x4*>(&row[cb ^ sw]) = w;
        }
    }
    __syncthreads();

    // MFMA: 2x2 wave tiling. wm = wv>>1 owns rows [wm*64,+64), wn = wv&1 owns p [wn*64,+64).
    int wm = wv >> 1, wn = wv & 1;
    f32x4 acc[4][4];
    #pragma unroll
    for (int mf = 0; mf < 4; ++mf)
        #pragma unroll
        for (int nfl = 0; nfl < 4; ++nfl) { f32x4 z = {0.f,0.f,0.f,0.f}; acc[mf][nfl] = z; }

    #pragma unroll 2
    for (int kt = 0; kt < 4; ++kt) {
        short8 ah[4], al[4];
        #pragma unroll
        for (int mf = 0; mf < 4; ++mf) {
            int mfg = wm * 4 + mf;
            U4S8 t;
            t.u = *reinterpret_cast<const u32x4*>(&wsu[WCF + (kt * 8 + mfg) * 256 + lane * 4]);
            ah[mf] = t.s;
            t.u = *reinterpret_cast<const u32x4*>(&wsu[WCF + 10240 + (kt * 8 + mfg) * 256 + lane * 4]);
            al[mf] = t.s;
        }
        #pragma unroll
        for (int nfl = 0; nfl < 4; ++nfl) {
            int p = (wn * 4 + nfl) * 16 + (lane & 15);
            const uint32_t* row = xs + p * 128;
            short8 bh, bl;
            load_bfrag(row, kt * 32 + ((lane >> 4) << 3), (p & 7) << 2, bh, bl);
            #pragma unroll
            for (int mf = 0; mf < 4; ++mf) {
                MFMA(acc[mf][nfl], ah[mf], bh);
                MFMA(acc[mf][nfl], ah[mf], bl);
                MFMA(acc[mf][nfl], al[mf], bh);
            }
        }
    }
    // states K-tile (kt = 4): hi plane only (states are bf16-rounded anyway)
    {
        short8 ah[4];
        #pragma unroll
        for (int mf = 0; mf < 4; ++mf) {
            int mfg = wm * 4 + mf;
            U4S8 t;
            t.u = *reinterpret_cast<const u32x4*>(&wsu[WCF + (32 + mfg) * 256 + lane * 4]);
            ah[mf] = t.s;
        }
        int grp = lane >> 4;
        #pragma unroll
        for (int nfl = 0; nfl < 4; ++nfl) {
            int p = (wn * 4 + nfl) * 16 + (lane & 15);
            U4S8 t;
            t.u = *reinterpret_cast<const u32x4*>(&stl[p * 32 + grp * 8]);
            short8 bs = t.s;
            #pragma unroll
            for (int mf = 0; mf < 4; ++mf)
                MFMA(acc[mf][nfl], ah[mf], bs);
        }
    }

    // epilogue: + bias + residual, nontemporal stores
    {
        int q4 = (lane >> 4) << 2;
        #pragma unroll
        for (int mf = 0; mf < 4; ++mf) {
            int cb = wm * 64 + mf * 16 + q4;
            f32x4 bc = *reinterpret_cast<const f32x4*>(ws + BIASC + cb);
            #pragma unroll
            for (int j = 0; j < 4; ++j) {
                size_t rowa = (size_t)(cb + j) * LSEQ;
                #pragma unroll
                for (int nfl = 0; nfl < 4; ++nfl) {
                    int p = (wn * 4 + nfl) * 16 + (lane & 15);
                    float val = acc[mf][nfl][j] + bc[j] + xb[rowa + p];
                    __builtin_nontemporal_store(val, &ob[rowa + p]);
                }
            }
        }
    }
}

// ---------------------------------------------------------------------------
extern "C" void kernel_launch(void* const* d_in, const int* in_sizes, int n_in,
                              void* d_out, int out_size, void* d_ws, size_t ws_size,
                              hipStream_t stream)
{
    const float* x     = (const float*)d_in[0];
    const float* A     = (const float*)d_in[1];
    const float* Bm    = (const float*)d_in[2];
    const float* Cm    = (const float*)d_in[3];
    const float* Dv    = (const float*)d_in[4];
    const float* W_in  = (const float*)d_in[5];
    const float* b_in  = (const float*)d_in[6];
    const float* W_out = (const float*)d_in[7];
    const float* b_out = (const float*)d_in[8];
    const float* gamma = (const float*)d_in[9];
    const float* beta  = (const float*)d_in[10];
    float* ws  = (float*)d_ws;
    float* out = (float*)d_out;

    prep_kernel<<<dim3(45),  dim3(256), 0, stream>>>(Bm, Cm, Dv, W_in, b_in, W_out, b_out, ws);
    ln_u_kernel<<<dim3(512), dim3(256), 0, stream>>>(x, gamma, beta, ws);
    scan_kernel<<<dim3(512), dim3(64),  0, stream>>>(A, ws);
    out_kernel <<<dim3(512), dim3(256), 0, stream>>>(x, gamma, beta, out, ws);
}

// Round 5
// 147.799 us; speedup vs baseline: 1.2299x; 1.0773x over previous
//
#include <hip/hip_runtime.h>
#include <cstdint>

#define BATCH 16
#define CDIM  128
#define EDIM  256
#define SDIM  16
#define LSEQ  4096
#define LN_EPS 1e-5f

typedef __attribute__((ext_vector_type(8))) short short8;
typedef __attribute__((ext_vector_type(4))) float f32x4;
typedef __attribute__((ext_vector_type(4))) unsigned int u32x4;

// ---- ws layout (32-bit word offsets) ----
#define BIASC  20480        // fp32 bias_c [128]
#define BU     20608        // fp32 bu     [16]
#define WCF    20736        // K3 A-frags: plane(2) x kt(5) x mf(8) x lane(64) x 4 words
#define WUF    41216        // K1 A-frags: plane(2) x kt(4) x lane(64) x 4 words
#define U_OFF  65536        // u [B][L][S] fp32 (1048576 words)
#define HN_OFF 1114112      // packed hn images: 512 tiles x 16384 words (33.5 MB)

static __device__ __forceinline__ uint32_t umin_u32(uint32_t a, uint32_t b) { return a < b ? a : b; }

static __device__ __forceinline__ unsigned short f2bf(float f) {
    uint32_t u = __float_as_uint(f);
    uint32_t r = u + 0x7fffu + ((u >> 16) & 1u);   // RTNE
    return (unsigned short)(r >> 16);
}
static __device__ __forceinline__ float bf2f(unsigned short h) {
    return __uint_as_float(((uint32_t)h) << 16);
}
// truncation split: hi = trunc16(v), lo = RTNE(v - hi).
static __device__ __forceinline__ uint32_t pack_split_trunc(float v) {
    uint32_t u = __float_as_uint(v);
    float hi_f = __uint_as_float(u & 0xffff0000u);
    unsigned short lo = f2bf(v - hi_f);
    return (u >> 16) | ((uint32_t)lo << 16);       // low16 = hi plane, high16 = lo plane
}
static __device__ __forceinline__ uint32_t pack2bf(float a, float b) {
    return (uint32_t)f2bf(a) | ((uint32_t)f2bf(b) << 16);
}

union U4S8 { u32x4 u; short8 s; };

static __device__ __forceinline__ uint32_t permb(uint32_t a, uint32_t b, uint32_t sel) {
    return __builtin_amdgcn_perm(a, b, sel);
}

static __device__ __forceinline__ void load_bfrag(const uint32_t* row, int cb, int sw,
                                                  short8& bh, short8& bl) {
    u32x4 A = *reinterpret_cast<const u32x4*>(&row[(cb) ^ sw]);
    u32x4 B = *reinterpret_cast<const u32x4*>(&row[(cb + 4) ^ sw]);
    U4S8 h, l;
    h.u[0] = permb(A[1], A[0], 0x05040100u);
    h.u[1] = permb(A[3], A[2], 0x05040100u);
    h.u[2] = permb(B[1], B[0], 0x05040100u);
    h.u[3] = permb(B[3], B[2], 0x05040100u);
    l.u[0] = permb(A[1], A[0], 0x07060302u);
    l.u[1] = permb(A[3], A[2], 0x07060302u);
    l.u[2] = permb(B[1], B[0], 0x07060302u);
    l.u[3] = permb(B[3], B[2], 0x07060302u);
    bh = h.s; bl = l.s;
}

#define MFMA(acc, a, b) acc = __builtin_amdgcn_mfma_f32_16x16x32_bf16((a), (b), (acc), 0, 0, 0)

#define ROT_I(VAL, K) __builtin_amdgcn_mov_dpp((VAL), 0x120 + (K), 0xF, 0xF, true)
#define REP15(M) M(1) M(2) M(3) M(4) M(5) M(6) M(7) M(8) M(9) M(10) M(11) M(12) M(13) M(14) M(15)

#if __has_builtin(__builtin_amdgcn_rcpf)
  #define RCPF(x) __builtin_amdgcn_rcpf(x)
#else
  #define RCPF(x) (1.0f / (x))
#endif

#define SCAN_STEP(ST, UT) { \
    float a0 = fmaf(Ak[0], (ST), (UT)); \
    float a1 = 0.f, a2 = 0.f, a3 = 0.f; \
    { \
        float r_; \
        r_ = __int_as_float(ROT_I(__float_as_int(ST), 1));  a1 = fmaf(Ak[1],  r_, a1); \
        r_ = __int_as_float(ROT_I(__float_as_int(ST), 2));  a2 = fmaf(Ak[2],  r_, a2); \
        r_ = __int_as_float(ROT_I(__float_as_int(ST), 3));  a3 = fmaf(Ak[3],  r_, a3); \
        r_ = __int_as_float(ROT_I(__float_as_int(ST), 4));  a0 = fmaf(Ak[4],  r_, a0); \
        r_ = __int_as_float(ROT_I(__float_as_int(ST), 5));  a1 = fmaf(Ak[5],  r_, a1); \
        r_ = __int_as_float(ROT_I(__float_as_int(ST), 6));  a2 = fmaf(Ak[6],  r_, a2); \
        r_ = __int_as_float(ROT_I(__float_as_int(ST), 7));  a3 = fmaf(Ak[7],  r_, a3); \
        r_ = __int_as_float(ROT_I(__float_as_int(ST), 8));  a0 = fmaf(Ak[8],  r_, a0); \
        r_ = __int_as_float(ROT_I(__float_as_int(ST), 9));  a1 = fmaf(Ak[9],  r_, a1); \
        r_ = __int_as_float(ROT_I(__float_as_int(ST), 10)); a2 = fmaf(Ak[10], r_, a2); \
        r_ = __int_as_float(ROT_I(__float_as_int(ST), 11)); a3 = fmaf(Ak[11], r_, a3); \
        r_ = __int_as_float(ROT_I(__float_as_int(ST), 12)); a0 = fmaf(Ak[12], r_, a0); \
        r_ = __int_as_float(ROT_I(__float_as_int(ST), 13)); a1 = fmaf(Ak[13], r_, a1); \
        r_ = __int_as_float(ROT_I(__float_as_int(ST), 14)); a2 = fmaf(Ak[14], r_, a2); \
        r_ = __int_as_float(ROT_I(__float_as_int(ST), 15)); a3 = fmaf(Ak[15], r_, a3); \
    } \
    float X = (a0 + a2) + (a1 + a3); \
    float ex = __expf(X + X); \
    (ST) = fmaf(-2.f, RCPF(ex + 1.f), 1.f); }

// ---------------------------------------------------------------------------
// prep: split-bf16 MFMA A-fragments directly from the e-dots (R3, passed).
// ---------------------------------------------------------------------------
__global__ __launch_bounds__(256) void prep_kernel(
    const float* __restrict__ Bm, const float* __restrict__ Cm,
    const float* __restrict__ Dv, const float* __restrict__ W_in,
    const float* __restrict__ b_in, const float* __restrict__ W_out,
    const float* __restrict__ b_out, float* __restrict__ ws)
{
    uint32_t* wsu = (uint32_t*)ws;
    int blk = blockIdx.x, tid = threadIdx.x;
    if (blk < 40) {                       // K3 frag word-pairs, widx in [0,10240)
        int widx = blk * 256 + tid;
        int j2 = widx & 3;
        int l  = (widx >> 2) & 63;
        int mf = (widx >> 8) & 7;
        int kt = widx >> 11;              // 0..4
        int row = mf * 16 + (l & 15);
        int k0 = kt * 32 + ((l >> 4) << 3) + j2 * 2;
        float v0 = 0.f, v1 = 0.f;
        if (kt < 4) {
            #pragma unroll 4
            for (int e = 0; e < EDIM; ++e) {
                float wd = W_out[row * EDIM + e] * Dv[e];
                v0 = fmaf(wd, W_in[e * CDIM + k0], v0);
                v1 = fmaf(wd, W_in[e * CDIM + k0 + 1], v1);
            }
        } else {
            int s0 = k0 - 128;
            if (s0 < 16) {
                #pragma unroll 4
                for (int e = 0; e < EDIM; ++e) {
                    float wo = W_out[row * EDIM + e];
                    v0 = fmaf(wo, Cm[e * SDIM + s0], v0);
                    v1 = fmaf(wo, Cm[e * SDIM + s0 + 1], v1);
                }
            }
        }
        unsigned short h0 = f2bf(v0), h1 = f2bf(v1);
        unsigned short l0 = f2bf(v0 - bf2f(h0));
        unsigned short l1 = f2bf(v1 - bf2f(h1));
        wsu[WCF + widx]         = (uint32_t)h0 | ((uint32_t)h1 << 16);
        wsu[WCF + 10240 + widx] = (uint32_t)l0 | ((uint32_t)l1 << 16);
    } else if (blk < 44) {                // K1 (W_u) frag word-pairs, widx in [0,1024)
        int widx = (blk - 40) * 256 + tid;
        int j2 = widx & 3;
        int l  = (widx >> 2) & 63;
        int kt = (widx >> 8) & 3;
        int row = l & 15;
        int k0 = kt * 32 + ((l >> 4) << 3) + j2 * 2;
        float v0 = 0.f, v1 = 0.f;
        #pragma unroll 4
        for (int e = 0; e < EDIM; ++e) {
            float bm = Bm[row * EDIM + e];
            v0 = fmaf(bm, W_in[e * CDIM + k0], v0);
            v1 = fmaf(bm, W_in[e * CDIM + k0 + 1], v1);
        }
        unsigned short h0 = f2bf(v0), h1 = f2bf(v1);
        unsigned short l0 = f2bf(v0 - bf2f(h0));
        unsigned short l1 = f2bf(v1 - bf2f(h1));
        wsu[WUF + widx]        = (uint32_t)h0 | ((uint32_t)h1 << 16);
        wsu[WUF + 1024 + widx] = (uint32_t)l0 | ((uint32_t)l1 << 16);
    } else {                              // biases
        if (tid < 128) {
            float acc = b_out[tid];
            #pragma unroll 4
            for (int e = 0; e < EDIM; ++e)
                acc += W_out[tid * EDIM + e] * Dv[e] * b_in[e];
            ws[BIASC + tid] = acc;
        } else if (tid < 144) {
            int s = tid - 128;
            float acc = 0.f;
            #pragma unroll 4
            for (int e = 0; e < EDIM; ++e)
                acc += Bm[s * EDIM + e] * b_in[e];
            ws[BU + s] = acc;
        }
    }
}

// ---------------------------------------------------------------------------
// KA: LN + u = hn @ W_u^T + bu  (split-bf16 MFMA) + export packed hn image.
// ---------------------------------------------------------------------------
__global__ __launch_bounds__(256, 2) void ln_u_kernel(
    const float* __restrict__ x, const float* __restrict__ gamma,
    const float* __restrict__ beta, float* __restrict__ ws)
{
    __shared__ uint32_t xs[16384];           // 64 KB: [p][c] words, swizzle ^((p&7)<<2)
    __shared__ float scratch[2560];          // pr1[4][128] @0, pr2 @512 -> later ul[p*20+..]
    __shared__ float mu_s[128], rs_s[128];
    __shared__ float gb[256];

    int tid = threadIdx.x;
    int lane = tid & 63, wv = tid >> 6;
    int blk = blockIdx.x;
    int b  = blk >> 5;
    int P0 = (blk & 31) << 7;
    const float* xb = x + ((size_t)b * CDIM) * LSEQ + P0;
    uint32_t* wsu = (uint32_t*)ws;

    // A-frags (same for all waves)
    short8 auh[4], aul[4];
    #pragma unroll
    for (int kt = 0; kt < 4; ++kt) {
        U4S8 t;
        t.u = *reinterpret_cast<const u32x4*>(&wsu[WUF + kt * 256 + lane * 4]);
        auh[kt] = t.s;
        t.u = *reinterpret_cast<const u32x4*>(&wsu[WUF + 1024 + kt * 256 + lane * 4]);
        aul[kt] = t.s;
    }
    if (tid < 128) { gb[tid] = gamma[tid]; gb[128 + tid] = beta[tid]; }

    // stage x ([c][p] global -> [p][c] LDS swizzled) with folded LN partials
    int p4 = (tid & 31) << 2;
    {
        float sm0=0.f,sm1=0.f,sm2=0.f,sm3=0.f, sq0=0.f,sq1=0.f,sq2=0.f,sq3=0.f;
        #pragma unroll
        for (int it = 0; it < 16; ++it) {
            int c = it * 8 + (tid >> 5);
            f32x4 v = *reinterpret_cast<const f32x4*>(xb + (size_t)c * LSEQ + p4);
            sm0 += v[0]; sq0 += v[0]*v[0];
            sm1 += v[1]; sq1 += v[1]*v[1];
            sm2 += v[2]; sq2 += v[2]*v[2];
            sm3 += v[3]; sq3 += v[3]*v[3];
            #pragma unroll
            for (int j = 0; j < 4; ++j) {
                int p = p4 + j;
                xs[p * 128 + (c ^ ((p & 7) << 2))] = __float_as_uint(v[j]);
            }
        }
        sm0 += __shfl_xor(sm0, 32); sq0 += __shfl_xor(sq0, 32);
        sm1 += __shfl_xor(sm1, 32); sq1 += __shfl_xor(sq1, 32);
        sm2 += __shfl_xor(sm2, 32); sq2 += __shfl_xor(sq2, 32);
        sm3 += __shfl_xor(sm3, 32); sq3 += __shfl_xor(sq3, 32);
        if ((tid & 32) == 0) {
            float* pr1 = scratch, * pr2 = scratch + 512;
            pr1[wv * 128 + p4 + 0] = sm0; pr2[wv * 128 + p4 + 0] = sq0;
            pr1[wv * 128 + p4 + 1] = sm1; pr2[wv * 128 + p4 + 1] = sq1;
            pr1[wv * 128 + p4 + 2] = sm2; pr2[wv * 128 + p4 + 2] = sq2;
            pr1[wv * 128 + p4 + 3] = sm3; pr2[wv * 128 + p4 + 3] = sq3;
        }
    }
    __syncthreads();
    if (tid < 128) {
        const float* pr1 = scratch, * pr2 = scratch + 512;
        float s1 = pr1[tid] + pr1[128 + tid] + pr1[256 + tid] + pr1[384 + tid];
        float s2 = pr2[tid] + pr2[128 + tid] + pr2[256 + tid] + pr2[384 + tid];
        float mu = s1 * (1.f / 128.f);
        float var = s2 * (1.f / 128.f) - mu * mu;
        mu_s[tid] = mu; rs_s[tid] = rsqrtf(var + LN_EPS);
    }
    __syncthreads();

    // normalize + split-pack in place (truncation hi)
    {
        int p = tid & 127, half = tid >> 7, c0 = half * 64, sw = (p & 7) << 2;
        uint32_t* row = xs + p * 128;
        float mu = mu_s[p], rs = rs_s[p];
        #pragma unroll
        for (int it = 0; it < 16; ++it) {
            int cb = c0 + it * 4;
            u32x4 w = *reinterpret_cast<u32x4*>(&row[cb ^ sw]);
            #pragma unroll
            for (int j = 0; j < 4; ++j) {
                int c = cb + j;
                float val = (__uint_as_float(w[j]) - mu) * rs * gb[c] + gb[128 + c];
                w[j] = pack_split_trunc(val);
            }
            *reinterpret_cast<u32x4*>(&row[cb ^ sw]) = w;
        }
    }
    __syncthreads();

    // export packed hn image (coalesced, read back by KB)
    {
        uint32_t* hnp = wsu + HN_OFF + (size_t)blk * 16384;
        #pragma unroll
        for (int it = 0; it < 16; ++it) {
            int idx = it * 1024 + tid * 4;
            *reinterpret_cast<u32x4*>(hnp + idx) = *reinterpret_cast<const u32x4*>(xs + idx);
        }
    }

    // MFMA: wave wv handles nf = wv*2 + {0,1}; results to scratch (as ul[p*20+..])
    float* ul = scratch;
    #pragma unroll
    for (int nfi = 0; nfi < 2; ++nfi) {
        int nf = wv * 2 + nfi;
        int p = nf * 16 + (lane & 15);
        const uint32_t* row = xs + p * 128;
        int sw = (p & 7) << 2;
        f32x4 acc = {0.f, 0.f, 0.f, 0.f};
        #pragma unroll
        for (int kt = 0; kt < 4; ++kt) {
            short8 bh, bl;
            load_bfrag(row, kt * 32 + ((lane >> 4) << 3), sw, bh, bl);
            MFMA(acc, auh[kt], bh);
            MFMA(acc, auh[kt], bl);
            MFMA(acc, aul[kt], bh);
        }
        #pragma unroll
        for (int j = 0; j < 4; ++j)
            ul[p * 20 + ((lane >> 4) << 2) + j] = acc[j];
    }
    __syncthreads();

    // store u (+bu), coalesced float4
    {
        float* uptr = ws + U_OFF + (size_t)b * (LSEQ * SDIM);
        int s4 = (tid & 3) << 2;
        f32x4 buv = *reinterpret_cast<const f32x4*>(ws + BU + s4);
        #pragma unroll
        for (int it = 0; it < 2; ++it) {
            int p = it * 64 + (tid >> 2);
            f32x4 vv;
            #pragma unroll
            for (int j = 0; j < 4; ++j) vv[j] = ul[p * 20 + s4 + j];
            *reinterpret_cast<f32x4*>(uptr + ((size_t)(P0 + p)) * SDIM + s4) = vv + buv;
        }
    }
}

// ---------------------------------------------------------------------------
// KB: wave-specialized {hn-stage || in-block scan} + out-MFMA + residual.
// Waves 0-1: copy packed hn image into LDS, zero stl upper half.
// Waves 2-3: tanh scan, 8 groups x chunk 16, halo 32, states -> stl (bf16).
// ---------------------------------------------------------------------------
__global__ __launch_bounds__(256, 2) void scan_out_kernel(
    const float* __restrict__ x, const float* __restrict__ Amat,
    float* __restrict__ out, const float* __restrict__ ws)
{
    __shared__ uint32_t xs[16384];                 // 64 KB packed hn
    __shared__ unsigned short stl[4096];           // 8 KB: states bf16 [p][32], s>=16 zero

    int tid = threadIdx.x;
    int lane = tid & 63, wv = tid >> 6;
    int blk = blockIdx.x;
    int b  = blk >> 5;
    int P0 = (blk & 31) << 7;
    const float* xb = x   + ((size_t)b * CDIM) * LSEQ + P0;
    float*       ob = out + ((size_t)b * CDIM) * LSEQ + P0;
    const uint32_t* wsu = (const uint32_t*)ws;

    if (wv < 2) {
        // zero stl upper halves (p = wv*64+lane covers 0..127)
        {
            int p = wv * 64 + lane;
            u32x4 z = {0u, 0u, 0u, 0u};
            *reinterpret_cast<u32x4*>(&stl[p * 32 + 16]) = z;
            *reinterpret_cast<u32x4*>(&stl[p * 32 + 24]) = z;
        }
        // stage packed hn image (linear coalesced copy)
        const uint32_t* hnp = wsu + HN_OFF + (size_t)blk * 16384;
        #pragma unroll
        for (int it = 0; it < 32; ++it) {
            int idx4 = (it * 128 + wv * 64 + lane) * 4;
            *reinterpret_cast<u32x4*>(xs + idx4) =
                *reinterpret_cast<const u32x4*>(hnp + idx4);
        }
    } else {
        // scan: group g of 16 lanes, chunk 16 outputs, halo 32
        int s = lane & 15, g = (wv - 2) * 4 + (lane >> 4);   // 0..7
        float Ak[16];
        Ak[0] = Amat[s * 16 + s];
        {
            int pk;
            #define PERMLOAD(K) pk = ROT_I(s, K); Ak[K] = Amat[s * 16 + pk];
            REP15(PERMLOAD)
            #undef PERMLOAD
        }
        int t0 = P0 + g * 16;
        int tstart = t0 - 32;
        const float* up = ws + U_OFF;
        const uint32_t umax = (uint32_t)(BATCH * LSEQ * SDIM - 1);
        int ibase = (b * LSEQ + tstart) * SDIM + s;

        float ub[8];
        #pragma unroll
        for (int j = 0; j < 8; ++j)
            ub[j] = up[umin_u32((uint32_t)(ibase + j * 16), umax)];
        uint32_t loff = (uint32_t)(ibase + 128);

        float st = 0.f;
        // 32 halo steps (masked below t=0), ring prefetch
        for (int it = 0; it < 4; ++it) {
            int tb = tstart + it * 8;
            #pragma unroll
            for (int j = 0; j < 8; ++j) {
                float msk = (tb + j >= 0) ? 1.f : 0.f;
                float u_t = ub[j] * msk;
                ub[j] = up[umin_u32(loff, umax)];
                loff += 16u;
                SCAN_STEP(st, u_t)
            }
        }
        // 16 output steps -> stl (first 8 keep prefetching the next 8)
        #pragma unroll
        for (int j = 0; j < 8; ++j) {
            float u_t = ub[j];
            ub[j] = up[umin_u32(loff, umax)];
            loff += 16u;
            SCAN_STEP(st, u_t)
            stl[(g * 16 + j) * 32 + s] = f2bf(st);
        }
        #pragma unroll
        for (int j = 0; j < 8; ++j) {
            float u_t = ub[j];
            SCAN_STEP(st, u_t)
            stl[(g * 16 + 8 + j) * 32 + s] = f2bf(st);
        }
    }
    __syncthreads();

    // out-MFMA: 2x2 wave tiling (proven in R3)
    int wm = wv >> 1, wn = wv & 1;
    f32x4 acc[4][4];
    #pragma unroll
    for (int mf = 0; mf < 4; ++mf)
        #pragma unroll
        for (int nfl = 0; nfl < 4; ++nfl) { f32x4 z = {0.f,0.f,0.f,0.f}; acc[mf][nfl] = z; }

    #pragma unroll 2
    for (int kt = 0; kt < 4; ++kt) {
        short8 ah[4], al[4];
        #pragma unroll
        for (int mf = 0; mf < 4; ++mf) {
            int mfg = wm * 4 + mf;
            U4S8 t;
            t.u = *reinterpret_cast<const u32x4*>(&wsu[WCF + (kt * 8 + mfg) * 256 + lane * 4]);
            ah[mf] = t.s;
            t.u = *reinterpret_cast<const u32x4*>(&wsu[WCF + 10240 + (kt * 8 + mfg) * 256 + lane * 4]);
            al[mf] = t.s;
        }
        #pragma unroll
        for (int nfl = 0; nfl < 4; ++nfl) {
            int p = (wn * 4 + nfl) * 16 + (lane & 15);
            const uint32_t* row = xs + p * 128;
            short8 bh, bl;
            load_bfrag(row, kt * 32 + ((lane >> 4) << 3), (p & 7) << 2, bh, bl);
            #pragma unroll
            for (int mf = 0; mf < 4; ++mf) {
                MFMA(acc[mf][nfl], ah[mf], bh);
                MFMA(acc[mf][nfl], ah[mf], bl);
                MFMA(acc[mf][nfl], al[mf], bh);
            }
        }
    }
    // states K-tile (kt = 4): hi plane only
    {
        short8 ah[4];
        #pragma unroll
        for (int mf = 0; mf < 4; ++mf) {
            int mfg = wm * 4 + mf;
            U4S8 t;
            t.u = *reinterpret_cast<const u32x4*>(&wsu[WCF + (32 + mfg) * 256 + lane * 4]);
            ah[mf] = t.s;
        }
        int grp = lane >> 4;
        #pragma unroll
        for (int nfl = 0; nfl < 4; ++nfl) {
            int p = (wn * 4 + nfl) * 16 + (lane & 15);
            U4S8 t;
            t.u = *reinterpret_cast<const u32x4*>(&stl[p * 32 + grp * 8]);
            short8 bs = t.s;
            #pragma unroll
            for (int mf = 0; mf < 4; ++mf)
                MFMA(acc[mf][nfl], ah[mf], bs);
        }
    }

    // epilogue: + bias + residual, nontemporal stores
    {
        int q4 = (lane >> 4) << 2;
        #pragma unroll
        for (int mf = 0; mf < 4; ++mf) {
            int cb = wm * 64 + mf * 16 + q4;
            f32x4 bc = *reinterpret_cast<const f32x4*>(ws + BIASC + cb);
            #pragma unroll
            for (int j = 0; j < 4; ++j) {
                size_t rowa = (size_t)(cb + j) * LSEQ;
                #pragma unroll
                for (int nfl = 0; nfl < 4; ++nfl) {
                    int p = (wn * 4 + nfl) * 16 + (lane & 15);
                    float val = acc[mf][nfl][j] + bc[j] + xb[rowa + p];
                    __builtin_nontemporal_store(val, &ob[rowa + p]);
                }
            }
        }
    }
}

// ---------------------------------------------------------------------------
extern "C" void kernel_launch(void* const* d_in, const int* in_sizes, int n_in,
                              void* d_out, int out_size, void* d_ws, size_t ws_size,
                              hipStream_t stream)
{
    const float* x     = (const float*)d_in[0];
    const float* A     = (const float*)d_in[1];
    const float* Bm    = (const float*)d_in[2];
    const float* Cm    = (const float*)d_in[3];
    const float* Dv    = (const float*)d_in[4];
    const float* W_in  = (const float*)d_in[5];
    const float* b_in  = (const float*)d_in[6];
    const float* W_out = (const float*)d_in[7];
    const float* b_out = (const float*)d_in[8];
    const float* gamma = (const float*)d_in[9];
    const float* beta  = (const float*)d_in[10];
    float* ws  = (float*)d_ws;
    float* out = (float*)d_out;

    prep_kernel    <<<dim3(45),  dim3(256), 0, stream>>>(Bm, Cm, Dv, W_in, b_in, W_out, b_out, ws);
    ln_u_kernel    <<<dim3(512), dim3(256), 0, stream>>>(x, gamma, beta, ws);
    scan_out_kernel<<<dim3(512), dim3(256), 0, stream>>>(x, A, out, ws);
}

// Round 6
// 139.589 us; speedup vs baseline: 1.3023x; 1.0588x over previous
//
#include <hip/hip_runtime.h>
#include <cstdint>

#define BATCH 16
#define CDIM  128
#define EDIM  256
#define SDIM  16
#define LSEQ  4096
#define LN_EPS 1e-5f

typedef __attribute__((ext_vector_type(8))) short short8;
typedef __attribute__((ext_vector_type(4))) float f32x4;
typedef __attribute__((ext_vector_type(4))) unsigned int u32x4;

// ---- ws layout (32-bit word offsets) ----
#define BIASC  20480        // fp32 bias_c [128]
#define BU     20608        // fp32 bu     [16]
#define WCF    20736        // out A-frags: plane(2) x kt(5) x mf(8) x lane(64) x 4 words
#define WUF    41216        // u  A-frags: plane(2) x kt(4) x lane(64) x 4 words
#define U_OFF  65536        // u_halo [512 blk][32 q][16 s] fp32 (256 KB)

static __device__ __forceinline__ unsigned short f2bf(float f) {
    uint32_t u = __float_as_uint(f);
    uint32_t r = u + 0x7fffu + ((u >> 16) & 1u);   // RTNE
    return (unsigned short)(r >> 16);
}
static __device__ __forceinline__ float bf2f(unsigned short h) {
    return __uint_as_float(((uint32_t)h) << 16);
}
// truncation split: hi = trunc16(v), lo = RTNE(v - hi); low16 = hi plane, high16 = lo.
static __device__ __forceinline__ uint32_t pack_split_trunc(float v) {
    uint32_t u = __float_as_uint(v);
    float hi_f = __uint_as_float(u & 0xffff0000u);
    unsigned short lo = f2bf(v - hi_f);
    return (u >> 16) | ((uint32_t)lo << 16);
}

union U4S8 { u32x4 u; short8 s; };

static __device__ __forceinline__ uint32_t permb(uint32_t a, uint32_t b, uint32_t sel) {
    return __builtin_amdgcn_perm(a, b, sel);
}

// Extract hi/lo-plane B-frags from 8 packed words at swizzled row.
// sw = ((p>>1)&7)<<2 (word units).
static __device__ __forceinline__ void load_bfrag(const uint32_t* row, int cb, int sw,
                                                  short8& bh, short8& bl) {
    u32x4 A = *reinterpret_cast<const u32x4*>(&row[(cb) ^ sw]);
    u32x4 B = *reinterpret_cast<const u32x4*>(&row[(cb + 4) ^ sw]);
    U4S8 h, l;
    h.u[0] = permb(A[1], A[0], 0x05040100u);
    h.u[1] = permb(A[3], A[2], 0x05040100u);
    h.u[2] = permb(B[1], B[0], 0x05040100u);
    h.u[3] = permb(B[3], B[2], 0x05040100u);
    l.u[0] = permb(A[1], A[0], 0x07060302u);
    l.u[1] = permb(A[3], A[2], 0x07060302u);
    l.u[2] = permb(B[1], B[0], 0x07060302u);
    l.u[3] = permb(B[3], B[2], 0x07060302u);
    bh = h.s; bl = l.s;
}

#define MFMA(acc, a, b) acc = __builtin_amdgcn_mfma_f32_16x16x32_bf16((a), (b), (acc), 0, 0, 0)

#define ROT_I(VAL, K) __builtin_amdgcn_mov_dpp((VAL), 0x120 + (K), 0xF, 0xF, true)
#define REP15(M) M(1) M(2) M(3) M(4) M(5) M(6) M(7) M(8) M(9) M(10) M(11) M(12) M(13) M(14) M(15)

#if __has_builtin(__builtin_amdgcn_rcpf)
  #define RCPF(x) __builtin_amdgcn_rcpf(x)
#else
  #define RCPF(x) (1.0f / (x))
#endif

#define SCAN_STEP(ST, UT) { \
    float a0 = fmaf(Ak[0], (ST), (UT)); \
    float a1 = 0.f, a2 = 0.f, a3 = 0.f; \
    { \
        float r_; \
        r_ = __int_as_float(ROT_I(__float_as_int(ST), 1));  a1 = fmaf(Ak[1],  r_, a1); \
        r_ = __int_as_float(ROT_I(__float_as_int(ST), 2));  a2 = fmaf(Ak[2],  r_, a2); \
        r_ = __int_as_float(ROT_I(__float_as_int(ST), 3));  a3 = fmaf(Ak[3],  r_, a3); \
        r_ = __int_as_float(ROT_I(__float_as_int(ST), 4));  a0 = fmaf(Ak[4],  r_, a0); \
        r_ = __int_as_float(ROT_I(__float_as_int(ST), 5));  a1 = fmaf(Ak[5],  r_, a1); \
        r_ = __int_as_float(ROT_I(__float_as_int(ST), 6));  a2 = fmaf(Ak[6],  r_, a2); \
        r_ = __int_as_float(ROT_I(__float_as_int(ST), 7));  a3 = fmaf(Ak[7],  r_, a3); \
        r_ = __int_as_float(ROT_I(__float_as_int(ST), 8));  a0 = fmaf(Ak[8],  r_, a0); \
        r_ = __int_as_float(ROT_I(__float_as_int(ST), 9));  a1 = fmaf(Ak[9],  r_, a1); \
        r_ = __int_as_float(ROT_I(__float_as_int(ST), 10)); a2 = fmaf(Ak[10], r_, a2); \
        r_ = __int_as_float(ROT_I(__float_as_int(ST), 11)); a3 = fmaf(Ak[11], r_, a3); \
        r_ = __int_as_float(ROT_I(__float_as_int(ST), 12)); a0 = fmaf(Ak[12], r_, a0); \
        r_ = __int_as_float(ROT_I(__float_as_int(ST), 13)); a1 = fmaf(Ak[13], r_, a1); \
        r_ = __int_as_float(ROT_I(__float_as_int(ST), 14)); a2 = fmaf(Ak[14], r_, a2); \
        r_ = __int_as_float(ROT_I(__float_as_int(ST), 15)); a3 = fmaf(Ak[15], r_, a3); \
    } \
    float X = (a0 + a2) + (a1 + a3); \
    float ex = __expf(X + X); \
    (ST) = fmaf(-2.f, RCPF(ex + 1.f), 1.f); }

// ---------------------------------------------------------------------------
// prep: split-bf16 MFMA A-fragments directly from the e-dots (R3/R5, proven).
// ---------------------------------------------------------------------------
__global__ __launch_bounds__(256) void prep_kernel(
    const float* __restrict__ Bm, const float* __restrict__ Cm,
    const float* __restrict__ Dv, const float* __restrict__ W_in,
    const float* __restrict__ b_in, const float* __restrict__ W_out,
    const float* __restrict__ b_out, float* __restrict__ ws)
{
    uint32_t* wsu = (uint32_t*)ws;
    int blk = blockIdx.x, tid = threadIdx.x;
    if (blk < 40) {                       // out-frag word-pairs, widx in [0,10240)
        int widx = blk * 256 + tid;
        int j2 = widx & 3;
        int l  = (widx >> 2) & 63;
        int mf = (widx >> 8) & 7;
        int kt = widx >> 11;              // 0..4
        int row = mf * 16 + (l & 15);
        int k0 = kt * 32 + ((l >> 4) << 3) + j2 * 2;
        float v0 = 0.f, v1 = 0.f;
        if (kt < 4) {
            #pragma unroll 4
            for (int e = 0; e < EDIM; ++e) {
                float wd = W_out[row * EDIM + e] * Dv[e];
                v0 = fmaf(wd, W_in[e * CDIM + k0], v0);
                v1 = fmaf(wd, W_in[e * CDIM + k0 + 1], v1);
            }
        } else {
            int s0 = k0 - 128;
            if (s0 < 16) {
                #pragma unroll 4
                for (int e = 0; e < EDIM; ++e) {
                    float wo = W_out[row * EDIM + e];
                    v0 = fmaf(wo, Cm[e * SDIM + s0], v0);
                    v1 = fmaf(wo, Cm[e * SDIM + s0 + 1], v1);
                }
            }
        }
        unsigned short h0 = f2bf(v0), h1 = f2bf(v1);
        unsigned short l0 = f2bf(v0 - bf2f(h0));
        unsigned short l1 = f2bf(v1 - bf2f(h1));
        wsu[WCF + widx]         = (uint32_t)h0 | ((uint32_t)h1 << 16);
        wsu[WCF + 10240 + widx] = (uint32_t)l0 | ((uint32_t)l1 << 16);
    } else if (blk < 44) {                // u-frag (W_u) word-pairs, widx in [0,1024)
        int widx = (blk - 40) * 256 + tid;
        int j2 = widx & 3;
        int l  = (widx >> 2) & 63;
        int kt = (widx >> 8) & 3;
        int row = l & 15;
        int k0 = kt * 32 + ((l >> 4) << 3) + j2 * 2;
        float v0 = 0.f, v1 = 0.f;
        #pragma unroll 4
        for (int e = 0; e < EDIM; ++e) {
            float bm = Bm[row * EDIM + e];
            v0 = fmaf(bm, W_in[e * CDIM + k0], v0);
            v1 = fmaf(bm, W_in[e * CDIM + k0 + 1], v1);
        }
        unsigned short h0 = f2bf(v0), h1 = f2bf(v1);
        unsigned short l0 = f2bf(v0 - bf2f(h0));
        unsigned short l1 = f2bf(v1 - bf2f(h1));
        wsu[WUF + widx]        = (uint32_t)h0 | ((uint32_t)h1 << 16);
        wsu[WUF + 1024 + widx] = (uint32_t)l0 | ((uint32_t)l1 << 16);
    } else {                              // biases
        if (tid < 128) {
            float acc = b_out[tid];
            #pragma unroll 4
            for (int e = 0; e < EDIM; ++e)
                acc += W_out[tid * EDIM + e] * Dv[e] * b_in[e];
            ws[BIASC + tid] = acc;
        } else if (tid < 144) {
            int s = tid - 128;
            float acc = 0.f;
            #pragma unroll 4
            for (int e = 0; e < EDIM; ++e)
                acc += Bm[s * EDIM + e] * b_in[e];
            ws[BU + s] = acc;
        }
    }
}

// ---------------------------------------------------------------------------
// halo_kernel: per tile, LN + u for the LAST 32 positions only -> u_halo.
// Consumed by fused_kernel block blk+1 as its scan halo drive.
// ---------------------------------------------------------------------------
__global__ __launch_bounds__(256) void halo_kernel(
    const float* __restrict__ x, const float* __restrict__ gamma,
    const float* __restrict__ beta, float* __restrict__ ws)
{
    __shared__ uint32_t xs2[32 * 128];     // packed hn, rows q, sw=((q>>1)&7)<<2
    __shared__ float pr1[4][32], pr2[4][32];
    __shared__ float mu2[32], rs2[32];
    __shared__ float ulh[32 * 16];

    int t = threadIdx.x;
    int lane = t & 63, wv = t >> 6;
    int blk = blockIdx.x;
    int b  = blk >> 5;
    int P0 = (blk & 31) << 7;
    const float* xb = x + ((size_t)b * CDIM) * LSEQ + P0 + 96;
    const uint32_t* wsu = (const uint32_t*)ws;

    int q4 = 4 * ((t >> 3) & 7);
    f32x4 xr[4];
    float sm0=0.f,sm1=0.f,sm2=0.f,sm3=0.f, sq0=0.f,sq1=0.f,sq2=0.f,sq3=0.f;
    #pragma unroll
    for (int it = 0; it < 4; ++it) {
        int c = (t & 7) + 32 * wv + 8 * it;
        f32x4 v = *reinterpret_cast<const f32x4*>(xb + (size_t)c * LSEQ + q4);
        xr[it] = v;
        sm0 += v[0]; sq0 += v[0]*v[0];
        sm1 += v[1]; sq1 += v[1]*v[1];
        sm2 += v[2]; sq2 += v[2]*v[2];
        sm3 += v[3]; sq3 += v[3]*v[3];
    }
    sm0 += __shfl_xor(sm0,1); sm0 += __shfl_xor(sm0,2); sm0 += __shfl_xor(sm0,4);
    sm1 += __shfl_xor(sm1,1); sm1 += __shfl_xor(sm1,2); sm1 += __shfl_xor(sm1,4);
    sm2 += __shfl_xor(sm2,1); sm2 += __shfl_xor(sm2,2); sm2 += __shfl_xor(sm2,4);
    sm3 += __shfl_xor(sm3,1); sm3 += __shfl_xor(sm3,2); sm3 += __shfl_xor(sm3,4);
    sq0 += __shfl_xor(sq0,1); sq0 += __shfl_xor(sq0,2); sq0 += __shfl_xor(sq0,4);
    sq1 += __shfl_xor(sq1,1); sq1 += __shfl_xor(sq1,2); sq1 += __shfl_xor(sq1,4);
    sq2 += __shfl_xor(sq2,1); sq2 += __shfl_xor(sq2,2); sq2 += __shfl_xor(sq2,4);
    sq3 += __shfl_xor(sq3,1); sq3 += __shfl_xor(sq3,2); sq3 += __shfl_xor(sq3,4);
    if ((lane & 7) == 0) {
        pr1[wv][q4+0] = sm0; pr2[wv][q4+0] = sq0;
        pr1[wv][q4+1] = sm1; pr2[wv][q4+1] = sq1;
        pr1[wv][q4+2] = sm2; pr2[wv][q4+2] = sq2;
        pr1[wv][q4+3] = sm3; pr2[wv][q4+3] = sq3;
    }
    __syncthreads();
    if (t < 32) {
        float s1 = pr1[0][t] + pr1[1][t] + pr1[2][t] + pr1[3][t];
        float s2 = pr2[0][t] + pr2[1][t] + pr2[2][t] + pr2[3][t];
        float mu = s1 * (1.f / 128.f);
        float var = s2 * (1.f / 128.f) - mu * mu;
        mu2[t] = mu; rs2[t] = rsqrtf(var + LN_EPS);
    }
    __syncthreads();

    // normalize + pack from registers (single LDS write pass)
    {
        float mu_[4], rs_[4];
        #pragma unroll
        for (int j = 0; j < 4; ++j) { mu_[j] = mu2[q4+j]; rs_[j] = rs2[q4+j]; }
        #pragma unroll
        for (int it = 0; it < 4; ++it) {
            int c = (t & 7) + 32 * wv + 8 * it;
            float g = gamma[c], be = beta[c];
            #pragma unroll
            for (int j = 0; j < 4; ++j) {
                int q = q4 + j;
                float val = (xr[it][j] - mu_[j]) * rs_[j] * g + be;
                xs2[q * 128 + (c ^ (((q >> 1) & 7) << 2))] = pack_split_trunc(val);
            }
        }
    }
    __syncthreads();

    // u-MFMA on waves 0-1 (nf = wv): u = hn @ W_u^T + bu
    if (wv < 2) {
        short8 auh[4], aul[4];
        #pragma unroll
        for (int kt = 0; kt < 4; ++kt) {
            U4S8 tt;
            tt.u = *reinterpret_cast<const u32x4*>(&wsu[WUF + kt * 256 + lane * 4]);
            auh[kt] = tt.s;
            tt.u = *reinterpret_cast<const u32x4*>(&wsu[WUF + 1024 + kt * 256 + lane * 4]);
            aul[kt] = tt.s;
        }
        int q = wv * 16 + (lane & 15);
        const uint32_t* row = xs2 + q * 128;
        int sw = ((q >> 1) & 7) << 2;
        f32x4 acc = {0.f, 0.f, 0.f, 0.f};
        #pragma unroll
        for (int kt = 0; kt < 4; ++kt) {
            short8 bh, bl;
            load_bfrag(row, kt * 32 + ((lane >> 4) << 3), sw, bh, bl);
            MFMA(acc, auh[kt], bh);
            MFMA(acc, auh[kt], bl);
            MFMA(acc, aul[kt], bh);
        }
        int s4 = (lane >> 4) << 2;
        f32x4 bu4 = *reinterpret_cast<const f32x4*>(ws + BU + s4);
        #pragma unroll
        for (int j = 0; j < 4; ++j)
            ulh[q * 16 + s4 + j] = acc[j] + bu4[j];
    }
    __syncthreads();
    if (t < 128)
        *reinterpret_cast<f32x4*>(ws + U_OFF + (size_t)blk * 512 + t * 4) =
            *reinterpret_cast<const f32x4*>(ulh + t * 4);
}

// ---------------------------------------------------------------------------
// fused_kernel: stage x + wave-local LN + pack -> u-MFMA (own tile) + halo fill
// -> in-block scan -> out-MFMA -> epilogue (bias + reconstructed residual).
// ---------------------------------------------------------------------------
__global__ __launch_bounds__(256, 2) void fused_kernel(
    const float* __restrict__ x, const float* __restrict__ Amat,
    const float* __restrict__ gamma, const float* __restrict__ beta,
    float* __restrict__ out, const float* __restrict__ ws)
{
    __shared__ uint32_t xs[16384];                 // 64 KB packed hn, sw=((p>>1)&7)<<2
    __shared__ unsigned short ul[160 * 18];        // u bf16, rows t-P0+32, stride 18
    __shared__ unsigned short stl[128 * 32];       // states bf16 [p][32], s>=16 zero
    __shared__ float mu_s[128], sig_s[128];

    int t = threadIdx.x;
    int lane = t & 63, wv = t >> 6;
    int blk = blockIdx.x;
    int b  = blk >> 5;
    int P0 = (blk & 31) << 7;
    const float* xb = x   + ((size_t)b * CDIM) * LSEQ + P0;
    float*       ob = out + ((size_t)b * CDIM) * LSEQ + P0;
    const uint32_t* wsu = (const uint32_t*)ws;

    // ---- phase 1: stage (reg-hold) + wave-local LN + single packed LDS write ----
    int p4 = 4 * (t >> 3);
    {
        f32x4 xr[16];
        float sm0=0.f,sm1=0.f,sm2=0.f,sm3=0.f, sq0=0.f,sq1=0.f,sq2=0.f,sq3=0.f;
        #pragma unroll
        for (int it = 0; it < 16; ++it) {
            int c = (t & 7) + 8 * it;
            f32x4 v = *reinterpret_cast<const f32x4*>(xb + (size_t)c * LSEQ + p4);
            xr[it] = v;
            sm0 += v[0]; sq0 += v[0]*v[0];
            sm1 += v[1]; sq1 += v[1]*v[1];
            sm2 += v[2]; sq2 += v[2]*v[2];
            sm3 += v[3]; sq3 += v[3]*v[3];
        }
        sm0 += __shfl_xor(sm0,1); sm0 += __shfl_xor(sm0,2); sm0 += __shfl_xor(sm0,4);
        sm1 += __shfl_xor(sm1,1); sm1 += __shfl_xor(sm1,2); sm1 += __shfl_xor(sm1,4);
        sm2 += __shfl_xor(sm2,1); sm2 += __shfl_xor(sm2,2); sm2 += __shfl_xor(sm2,4);
        sm3 += __shfl_xor(sm3,1); sm3 += __shfl_xor(sm3,2); sm3 += __shfl_xor(sm3,4);
        sq0 += __shfl_xor(sq0,1); sq0 += __shfl_xor(sq0,2); sq0 += __shfl_xor(sq0,4);
        sq1 += __shfl_xor(sq1,1); sq1 += __shfl_xor(sq1,2); sq1 += __shfl_xor(sq1,4);
        sq2 += __shfl_xor(sq2,1); sq2 += __shfl_xor(sq2,2); sq2 += __shfl_xor(sq2,4);
        sq3 += __shfl_xor(sq3,1); sq3 += __shfl_xor(sq3,2); sq3 += __shfl_xor(sq3,4);
        float mu_[4], rs_[4], sg_[4];
        {
            float smv[4] = {sm0, sm1, sm2, sm3};
            float sqv[4] = {sq0, sq1, sq2, sq3};
            #pragma unroll
            for (int j = 0; j < 4; ++j) {
                float mu = smv[j] * (1.f / 128.f);
                float var = sqv[j] * (1.f / 128.f) - mu * mu;
                float rs = rsqrtf(var + LN_EPS);
                mu_[j] = mu; rs_[j] = rs; sg_[j] = RCPF(rs);
            }
        }
        if ((lane & 7) == 0) {
            #pragma unroll
            for (int j = 0; j < 4; ++j) { mu_s[p4+j] = mu_[j]; sig_s[p4+j] = sg_[j]; }
        }
        #pragma unroll
        for (int it = 0; it < 16; ++it) {
            int c = (t & 7) + 8 * it;
            float g = gamma[c], be = beta[c];
            #pragma unroll
            for (int j = 0; j < 4; ++j) {
                int p = p4 + j;
                float val = (xr[it][j] - mu_[j]) * rs_[j] * g + be;
                xs[p * 128 + (c ^ (((p >> 1) & 7) << 2))] = pack_split_trunc(val);
            }
        }
    }
    __syncthreads();

    // ---- phase 2: u-MFMA (own 128 pos) + halo-u fill + stl upper zero ----
    {
        // halo fill: rows 0..31 of ul from u_halo[blk-1] (masked at t<0 in scan)
        if (t < 128) {
            int src = (blk & 31) ? (blk - 1) : (blk > 0 ? blk : 0);
            f32x4 v = *reinterpret_cast<const f32x4*>(ws + U_OFF + (size_t)src * 512 + t * 4);
            int q = t >> 2, s0 = (t & 3) * 4;
            #pragma unroll
            for (int k = 0; k < 4; ++k)
                ul[q * 18 + s0 + k] = f2bf(v[k]);
        }
        // stl upper zero: words 8..15 of each 16-word row
        {
            uint32_t* stl32 = (uint32_t*)stl;
            int p = t >> 1, k0 = 8 + (t & 1) * 4;
            u32x4 z = {0u,0u,0u,0u};
            *reinterpret_cast<u32x4*>(&stl32[p * 16 + k0]) = z;
        }
        // u-MFMA: wave wv handles nf = wv*2 + {0,1}
        short8 auh[4], aul[4];
        #pragma unroll
        for (int kt = 0; kt < 4; ++kt) {
            U4S8 tt;
            tt.u = *reinterpret_cast<const u32x4*>(&wsu[WUF + kt * 256 + lane * 4]);
            auh[kt] = tt.s;
            tt.u = *reinterpret_cast<const u32x4*>(&wsu[WUF + 1024 + kt * 256 + lane * 4]);
            aul[kt] = tt.s;
        }
        int s4 = (lane >> 4) << 2;
        f32x4 bu4 = *reinterpret_cast<const f32x4*>(ws + BU + s4);
        #pragma unroll
        for (int nfi = 0; nfi < 2; ++nfi) {
            int nf = wv * 2 + nfi;
            int p = nf * 16 + (lane & 15);
            const uint32_t* row = xs + p * 128;
            int sw = ((p >> 1) & 7) << 2;
            f32x4 acc = {0.f, 0.f, 0.f, 0.f};
            #pragma unroll
            for (int kt = 0; kt < 4; ++kt) {
                short8 bh, bl;
                load_bfrag(row, kt * 32 + ((lane >> 4) << 3), sw, bh, bl);
                MFMA(acc, auh[kt], bh);
                MFMA(acc, auh[kt], bl);
                MFMA(acc, aul[kt], bh);
            }
            #pragma unroll
            for (int j = 0; j < 4; ++j)
                ul[(32 + p) * 18 + s4 + j] = f2bf(acc[j] + bu4[j]);
        }
    }
    __syncthreads();

    // ---- phase 3: scan. 16 groups x chunk 8, halo 32 (40 steps), all from LDS ----
    {
        int s = t & 15, g = t >> 4;
        float Ak[16];
        Ak[0] = Amat[s * 16 + s];
        {
            int pk;
            #define PERMLOAD(K) pk = ROT_I(s, K); Ak[K] = Amat[s * 16 + pk];
            REP15(PERMLOAD)
            #undef PERMLOAD
        }
        int r0 = 8 * g;
        float ub[8];
        #pragma unroll
        for (int j = 0; j < 8; ++j) ub[j] = bf2f(ul[(r0 + j) * 18 + s]);
        int rl = r0 + 8;
        int tbase = P0 + 8 * g - 32;
        float st = 0.f;
        #pragma unroll
        for (int it = 0; it < 4; ++it) {
            #pragma unroll
            for (int j = 0; j < 8; ++j) {
                float u_t = (tbase + it * 8 + j >= 0) ? ub[j] : 0.f;
                ub[j] = bf2f(ul[rl * 18 + s]);
                ++rl;
                SCAN_STEP(st, u_t)
            }
        }
        #pragma unroll
        for (int j = 0; j < 8; ++j) {
            SCAN_STEP(st, ub[j])
            stl[(r0 + j) * 32 + s] = f2bf(st);
        }
    }
    __syncthreads();

    // ---- phase 4: out-MFMA (2x2 wave tiling) + epilogue ----
    int wm = wv >> 1, wn = wv & 1;
    f32x4 acc[4][4];
    #pragma unroll
    for (int mf = 0; mf < 4; ++mf)
        #pragma unroll
        for (int nfl = 0; nfl < 4; ++nfl) { f32x4 z = {0.f,0.f,0.f,0.f}; acc[mf][nfl] = z; }

    #pragma unroll 2
    for (int kt = 0; kt < 4; ++kt) {
        short8 ah[4], al[4];
        #pragma unroll
        for (int mf = 0; mf < 4; ++mf) {
            int mfg = wm * 4 + mf;
            U4S8 tt;
            tt.u = *reinterpret_cast<const u32x4*>(&wsu[WCF + (kt * 8 + mfg) * 256 + lane * 4]);
            ah[mf] = tt.s;
            tt.u = *reinterpret_cast<const u32x4*>(&wsu[WCF + 10240 + (kt * 8 + mfg) * 256 + lane * 4]);
            al[mf] = tt.s;
        }
        #pragma unroll
        for (int nfl = 0; nfl < 4; ++nfl) {
            int p = (wn * 4 + nfl) * 16 + (lane & 15);
            const uint32_t* row = xs + p * 128;
            short8 bh, bl;
            load_bfrag(row, kt * 32 + ((lane >> 4) << 3), ((p >> 1) & 7) << 2, bh, bl);
            #pragma unroll
            for (int mf = 0; mf < 4; ++mf) {
                MFMA(acc[mf][nfl], ah[mf], bh);
                MFMA(acc[mf][nfl], ah[mf], bl);
                MFMA(acc[mf][nfl], al[mf], bh);
            }
        }
    }
    // states K-tile (kt = 4): hi plane only
    {
        short8 ah[4];
        #pragma unroll
        for (int mf = 0; mf < 4; ++mf) {
            int mfg = wm * 4 + mf;
            U4S8 tt;
            tt.u = *reinterpret_cast<const u32x4*>(&wsu[WCF + (32 + mfg) * 256 + lane * 4]);
            ah[mf] = tt.s;
        }
        int grp = lane >> 4;
        #pragma unroll
        for (int nfl = 0; nfl < 4; ++nfl) {
            int p = (wn * 4 + nfl) * 16 + (lane & 15);
            U4S8 tt;
            tt.u = *reinterpret_cast<const u32x4*>(&stl[p * 32 + grp * 8]);
            short8 bs = tt.s;
            #pragma unroll
            for (int mf = 0; mf < 4; ++mf)
                MFMA(acc[mf][nfl], ah[mf], bs);
        }
    }

    // epilogue: + bias + residual (x reconstructed from packed hn), nt stores
    {
        int q4 = (lane >> 4) << 2;
        float sgp[4], mup[4];
        #pragma unroll
        for (int nfl = 0; nfl < 4; ++nfl) {
            int p = (wn * 4 + nfl) * 16 + (lane & 15);
            sgp[nfl] = sig_s[p]; mup[nfl] = mu_s[p];
        }
        #pragma unroll
        for (int mf = 0; mf < 4; ++mf) {
            int cb = wm * 64 + mf * 16 + q4;
            f32x4 bc = *reinterpret_cast<const f32x4*>(ws + BIASC + cb);
            #pragma unroll
            for (int j = 0; j < 4; ++j) {
                int c = cb + j;
                float ig = RCPF(gamma[c]);
                float be = beta[c];
                size_t rowa = (size_t)c * LSEQ;
                #pragma unroll
                for (int nfl = 0; nfl < 4; ++nfl) {
                    int p = (wn * 4 + nfl) * 16 + (lane & 15);
                    uint32_t w = xs[p * 128 + (c ^ (((p >> 1) & 7) << 2))];
                    float hn = __uint_as_float(w << 16) + __uint_as_float(w & 0xffff0000u);
                    float xrc = fmaf((hn - be) * ig, sgp[nfl], mup[nfl]);
                    float val = acc[mf][nfl][j] + bc[j] + xrc;
                    __builtin_nontemporal_store(val, &ob[rowa + p]);
                }
            }
        }
    }
}

// ---------------------------------------------------------------------------
extern "C" void kernel_launch(void* const* d_in, const int* in_sizes, int n_in,
                              void* d_out, int out_size, void* d_ws, size_t ws_size,
                              hipStream_t stream)
{
    const float* x     = (const float*)d_in[0];
    const float* A     = (const float*)d_in[1];
    const float* Bm    = (const float*)d_in[2];
    const float* Cm    = (const float*)d_in[3];
    const float* Dv    = (const float*)d_in[4];
    const float* W_in  = (const float*)d_in[5];
    const float* b_in  = (const float*)d_in[6];
    const float* W_out = (const float*)d_in[7];
    const float* b_out = (const float*)d_in[8];
    const float* gamma = (const float*)d_in[9];
    const float* beta  = (const float*)d_in[10];
    float* ws  = (float*)d_ws;
    float* out = (float*)d_out;

    prep_kernel <<<dim3(45),  dim3(256), 0, stream>>>(Bm, Cm, Dv, W_in, b_in, W_out, b_out, ws);
    halo_kernel <<<dim3(512), dim3(256), 0, stream>>>(x, gamma, beta, ws);
    fused_kernel<<<dim3(512), dim3(256), 0, stream>>>(x, A, gamma, beta, out, ws);
}

// Round 9
// 134.351 us; speedup vs baseline: 1.3530x; 1.0390x over previous
//
#include <hip/hip_runtime.h>
#include <cstdint>

#define BATCH 16
#define CDIM  128
#define EDIM  256
#define SDIM  16
#define LSEQ  4096
#define LN_EPS 1e-5f

typedef __attribute__((ext_vector_type(8))) short short8;
typedef __attribute__((ext_vector_type(4))) float f32x4;
typedef __attribute__((ext_vector_type(4))) unsigned int u32x4;

// ---- ws layout (32-bit word offsets) ----
#define BIASC  20480        // fp32 bias_c [128]
#define BU     20608        // fp32 bu     [16]
#define WCF    20736        // out A-frags: kt(5) x mf(8) x lane(64) x 4 words (bf16 pairs)
#define WUF    41216        // u  A-frags: kt(4) x lane(64) x 4 words

static __device__ __forceinline__ unsigned short f2bf(float f) {
    uint32_t u = __float_as_uint(f);
    uint32_t r = u + 0x7fffu + ((u >> 16) & 1u);   // RTNE
    return (unsigned short)(r >> 16);
}
static __device__ __forceinline__ float bf2f(unsigned short h) {
    return __uint_as_float(((uint32_t)h) << 16);
}
static __device__ __forceinline__ uint32_t pack2bf(float a, float b) {
    return (uint32_t)f2bf(a) | ((uint32_t)f2bf(b) << 16);
}

union U4S8 { u32x4 u; short8 s; };

#define MFMA(acc, a, b) acc = __builtin_amdgcn_mfma_f32_16x16x32_bf16((a), (b), (acc), 0, 0, 0)

#define ROT_I(VAL, K) __builtin_amdgcn_mov_dpp((VAL), 0x120 + (K), 0xF, 0xF, true)
#define REP15(M) M(1) M(2) M(3) M(4) M(5) M(6) M(7) M(8) M(9) M(10) M(11) M(12) M(13) M(14) M(15)

#if __has_builtin(__builtin_amdgcn_rcpf)
  #define RCPF(x) __builtin_amdgcn_rcpf(x)
#else
  #define RCPF(x) (1.0f / (x))
#endif

#define SCAN_STEP(ST, UT) { \
    float a0 = fmaf(Ak[0], (ST), (UT)); \
    float a1 = 0.f, a2 = 0.f, a3 = 0.f; \
    { \
        float r_; \
        r_ = __int_as_float(ROT_I(__float_as_int(ST), 1));  a1 = fmaf(Ak[1],  r_, a1); \
        r_ = __int_as_float(ROT_I(__float_as_int(ST), 2));  a2 = fmaf(Ak[2],  r_, a2); \
        r_ = __int_as_float(ROT_I(__float_as_int(ST), 3));  a3 = fmaf(Ak[3],  r_, a3); \
        r_ = __int_as_float(ROT_I(__float_as_int(ST), 4));  a0 = fmaf(Ak[4],  r_, a0); \
        r_ = __int_as_float(ROT_I(__float_as_int(ST), 5));  a1 = fmaf(Ak[5],  r_, a1); \
        r_ = __int_as_float(ROT_I(__float_as_int(ST), 6));  a2 = fmaf(Ak[6],  r_, a2); \
        r_ = __int_as_float(ROT_I(__float_as_int(ST), 7));  a3 = fmaf(Ak[7],  r_, a3); \
        r_ = __int_as_float(ROT_I(__float_as_int(ST), 8));  a0 = fmaf(Ak[8],  r_, a0); \
        r_ = __int_as_float(ROT_I(__float_as_int(ST), 9));  a1 = fmaf(Ak[9],  r_, a1); \
        r_ = __int_as_float(ROT_I(__float_as_int(ST), 10)); a2 = fmaf(Ak[10], r_, a2); \
        r_ = __int_as_float(ROT_I(__float_as_int(ST), 11)); a3 = fmaf(Ak[11], r_, a3); \
        r_ = __int_as_float(ROT_I(__float_as_int(ST), 12)); a0 = fmaf(Ak[12], r_, a0); \
        r_ = __int_as_float(ROT_I(__float_as_int(ST), 13)); a1 = fmaf(Ak[13], r_, a1); \
        r_ = __int_as_float(ROT_I(__float_as_int(ST), 14)); a2 = fmaf(Ak[14], r_, a2); \
        r_ = __int_as_float(ROT_I(__float_as_int(ST), 15)); a3 = fmaf(Ak[15], r_, a3); \
    } \
    float X = (a0 + a2) + (a1 + a3); \
    float ex = __expf(X + X); \
    (ST) = fmaf(-2.f, RCPF(ex + 1.f), 1.f); }

// ---------------------------------------------------------------------------
// prep: single-plane bf16 MFMA A-fragments directly from the e-dots.
// ---------------------------------------------------------------------------
__global__ __launch_bounds__(256) void prep_kernel(
    const float* __restrict__ Bm, const float* __restrict__ Cm,
    const float* __restrict__ Dv, const float* __restrict__ W_in,
    const float* __restrict__ b_in, const float* __restrict__ W_out,
    const float* __restrict__ b_out, float* __restrict__ ws)
{
    uint32_t* wsu = (uint32_t*)ws;
    int blk = blockIdx.x, tid = threadIdx.x;
    if (blk < 40) {                       // out-frag words, widx in [0,10240)
        int widx = blk * 256 + tid;
        int j2 = widx & 3;
        int l  = (widx >> 2) & 63;
        int mf = (widx >> 8) & 7;
        int kt = widx >> 11;              // 0..4
        int row = mf * 16 + (l & 15);
        int k0 = kt * 32 + ((l >> 4) << 3) + j2 * 2;
        float v0 = 0.f, v1 = 0.f;
        if (kt < 4) {
            #pragma unroll 4
            for (int e = 0; e < EDIM; ++e) {
                float wd = W_out[row * EDIM + e] * Dv[e];
                v0 = fmaf(wd, W_in[e * CDIM + k0], v0);
                v1 = fmaf(wd, W_in[e * CDIM + k0 + 1], v1);
            }
        } else {
            int s0 = k0 - 128;
            if (s0 < 16) {
                #pragma unroll 4
                for (int e = 0; e < EDIM; ++e) {
                    float wo = W_out[row * EDIM + e];
                    v0 = fmaf(wo, Cm[e * SDIM + s0], v0);
                    v1 = fmaf(wo, Cm[e * SDIM + s0 + 1], v1);
                }
            }
        }
        wsu[WCF + widx] = pack2bf(v0, v1);
    } else if (blk < 44) {                // u-frag (W_u) words, widx in [0,1024)
        int widx = (blk - 40) * 256 + tid;
        int j2 = widx & 3;
        int l  = (widx >> 2) & 63;
        int kt = (widx >> 8) & 3;
        int row = l & 15;
        int k0 = kt * 32 + ((l >> 4) << 3) + j2 * 2;
        float v0 = 0.f, v1 = 0.f;
        #pragma unroll 4
        for (int e = 0; e < EDIM; ++e) {
            float bm = Bm[row * EDIM + e];
            v0 = fmaf(bm, W_in[e * CDIM + k0], v0);
            v1 = fmaf(bm, W_in[e * CDIM + k0 + 1], v1);
        }
        wsu[WUF + widx] = pack2bf(v0, v1);
    } else {                              // biases
        if (tid < 128) {
            float acc = b_out[tid];
            #pragma unroll 4
            for (int e = 0; e < EDIM; ++e)
                acc += W_out[tid * EDIM + e] * Dv[e] * b_in[e];
            ws[BIASC + tid] = acc;
        } else if (tid < 144) {
            int s = tid - 128;
            float acc = 0.f;
            #pragma unroll 4
            for (int e = 0; e < EDIM; ++e)
                acc += Bm[s * EDIM + e] * b_in[e];
            ws[BU + s] = acc;
        }
    }
}

// ---------------------------------------------------------------------------
// fused: 160-row tile (32-row in-block halo).
//   phase 1: stage x -> LN (16-thread shfl groups) -> bf16 pack (b128 writes)
//   phase 2: u-MFMA for all 160 rows -> ul (bf16); zero stl upper
//   phase 3: in-block scan (16 groups x 8 outputs, 32 halo steps)
//   phase 4: out-MFMA (single-plane) + bias + x residual re-read
// xs rows: r in [0,160) = positions P0-32 .. P0+127 (clamped at P0=0, masked).
// ---------------------------------------------------------------------------
__global__ __launch_bounds__(256, 2) void fused_kernel(
    const float* __restrict__ x, const float* __restrict__ Amat,
    const float* __restrict__ gamma, const float* __restrict__ beta,
    float* __restrict__ out, const float* __restrict__ ws)
{
    __shared__ unsigned short xs_h[160 * 136];     // 43.5 KB: row stride 136 halves (68 words)
    __shared__ unsigned short ul[160 * 18];        // 5.8 KB: u bf16
    __shared__ unsigned short stl[128 * 40];       // 10.2 KB: states bf16, s>=16 zero

    int t = threadIdx.x;
    int lane = t & 63, wv = t >> 6;
    int blk = blockIdx.x;
    int b  = blk >> 5;
    int P0 = (blk & 31) << 7;
    const float* xg = x + ((size_t)b * CDIM) * LSEQ;
    float*       ob = out + ((size_t)b * CDIM) * LSEQ + P0;
    const uint32_t* wsu = (const uint32_t*)ws;
    uint32_t* xs32 = (uint32_t*)xs_h;

    // ---- phase 1: stage + LN + bf16 pack ----
    {
        int cslot = t & 15, pg = t >> 4;
        int cb = cslot * 8;
        f32x4 g0 = *reinterpret_cast<const f32x4*>(&gamma[cb]);
        f32x4 g1 = *reinterpret_cast<const f32x4*>(&gamma[cb + 4]);
        f32x4 be0 = *reinterpret_cast<const f32x4*>(&beta[cb]);
        f32x4 be1 = *reinterpret_cast<const f32x4*>(&beta[cb + 4]);
        #pragma unroll
        for (int pit = 0; pit < 3; ++pit) {
            int p4 = 4 * (pg + 16 * pit);
            if (p4 < 160) {
                int gp4 = P0 - 32 + p4; if (gp4 < 0) gp4 = 0;
                f32x4 xr[8];
                #pragma unroll
                for (int i = 0; i < 8; ++i)
                    xr[i] = *reinterpret_cast<const f32x4*>(xg + (size_t)(cb + i) * LSEQ + gp4);
                float sm[4] = {0.f,0.f,0.f,0.f}, sq[4] = {0.f,0.f,0.f,0.f};
                #pragma unroll
                for (int i = 0; i < 8; ++i)
                    #pragma unroll
                    for (int j = 0; j < 4; ++j) {
                        float v = xr[i][j];
                        sm[j] += v; sq[j] += v * v;
                    }
                #pragma unroll
                for (int j = 0; j < 4; ++j) {
                    sm[j] += __shfl_xor(sm[j], 1); sq[j] += __shfl_xor(sq[j], 1);
                    sm[j] += __shfl_xor(sm[j], 2); sq[j] += __shfl_xor(sq[j], 2);
                    sm[j] += __shfl_xor(sm[j], 4); sq[j] += __shfl_xor(sq[j], 4);
                    sm[j] += __shfl_xor(sm[j], 8); sq[j] += __shfl_xor(sq[j], 8);
                }
                #pragma unroll
                for (int j = 0; j < 4; ++j) {
                    float mu = sm[j] * (1.f / 128.f);
                    float var = sq[j] * (1.f / 128.f) - mu * mu;
                    float rs = rsqrtf(var + LN_EPS);
                    u32x4 w;
                    #pragma unroll
                    for (int i2 = 0; i2 < 4; ++i2) {
                        float a0 = (xr[2*i2][j]   - mu) * rs;
                        float a1 = (xr[2*i2+1][j] - mu) * rs;
                        float gA = (2*i2   < 4) ? g0[2*i2]       : g1[2*i2-4];
                        float gB = (2*i2+1 < 4) ? g0[2*i2+1]     : g1[2*i2-3];
                        float bA = (2*i2   < 4) ? be0[2*i2]      : be1[2*i2-4];
                        float bB = (2*i2+1 < 4) ? be0[2*i2+1]    : be1[2*i2-3];
                        w[i2] = pack2bf(fmaf(a0, gA, bA), fmaf(a1, gB, bB));
                    }
                    *reinterpret_cast<u32x4*>(&xs32[(p4 + j) * 68 + cslot * 4]) = w;
                }
            }
        }
    }
    __syncthreads();

    // ---- phase 2: u-MFMA (160 rows, 10 n-frags) + stl upper zero ----
    {
        if (t < 128) {      // zero stl halves 16..31 of row t
            uint32_t* stl32 = (uint32_t*)stl;
            u32x4 z = {0u,0u,0u,0u};
            *reinterpret_cast<u32x4*>(&stl32[t * 20 + 8]) = z;
            *reinterpret_cast<u32x4*>(&stl32[t * 20 + 12]) = z;
        }
        short8 au[4];
        #pragma unroll
        for (int kt = 0; kt < 4; ++kt) {
            U4S8 tt;
            tt.u = *reinterpret_cast<const u32x4*>(&wsu[WUF + kt * 256 + lane * 4]);
            au[kt] = tt.s;
        }
        int s4 = (lane >> 4) << 2;
        f32x4 bu4 = *reinterpret_cast<const f32x4*>(ws + BU + s4);
        #pragma unroll
        for (int i = 0; i < 3; ++i) {
            int nf = wv + 4 * i;
            if (nf < 10) {
                int r = nf * 16 + (lane & 15);
                const uint32_t* row = xs32 + r * 68;
                f32x4 acc = {0.f, 0.f, 0.f, 0.f};
                #pragma unroll
                for (int kt = 0; kt < 4; ++kt) {
                    U4S8 tt;
                    tt.u = *reinterpret_cast<const u32x4*>(&row[kt * 16 + ((lane >> 4) << 2)]);
                    MFMA(acc, au[kt], tt.s);
                }
                #pragma unroll
                for (int j = 0; j < 4; ++j)
                    ul[r * 18 + s4 + j] = f2bf(acc[j] + bu4[j]);
            }
        }
    }
    __syncthreads();

    // ---- phase 3: scan. 16 groups x 8 outputs, 32 halo steps, all from LDS ----
    {
        int s = t & 15, g = t >> 4;
        float Ak[16];
        Ak[0] = Amat[s * 16 + s];
        {
            int pk;
            #define PERMLOAD(K) pk = ROT_I(s, K); Ak[K] = Amat[s * 16 + pk];
            REP15(PERMLOAD)
            #undef PERMLOAD
        }
        int r0 = 8 * g;
        float ub[8];
        #pragma unroll
        for (int j = 0; j < 8; ++j) ub[j] = bf2f(ul[(r0 + j) * 18 + s]);
        int rl = r0 + 8;
        int tbase = P0 - 32 + r0;
        float st = 0.f;
        #pragma unroll
        for (int it = 0; it < 4; ++it) {
            #pragma unroll
            for (int j = 0; j < 8; ++j) {
                float u_t = (tbase + it * 8 + j >= 0) ? ub[j] : 0.f;
                ub[j] = bf2f(ul[rl * 18 + s]);
                ++rl;
                SCAN_STEP(st, u_t)
            }
        }
        #pragma unroll
        for (int j = 0; j < 8; ++j) {
            SCAN_STEP(st, ub[j])
            stl[(r0 + j) * 40 + s] = f2bf(st);
        }
    }
    __syncthreads();

    // ---- phase 4: out-MFMA (single-plane) + epilogue ----
    int wm = wv >> 1, wn = wv & 1;
    int grp = lane >> 4;
    f32x4 acc[4][4];
    #pragma unroll
    for (int mf = 0; mf < 4; ++mf)
        #pragma unroll
        for (int nfl = 0; nfl < 4; ++nfl) { f32x4 z = {0.f,0.f,0.f,0.f}; acc[mf][nfl] = z; }

    #pragma unroll
    for (int kt = 0; kt < 4; ++kt) {
        short8 ah[4];
        #pragma unroll
        for (int mf = 0; mf < 4; ++mf) {
            U4S8 tt;
            tt.u = *reinterpret_cast<const u32x4*>(&wsu[WCF + (kt * 8 + wm * 4 + mf) * 256 + lane * 4]);
            ah[mf] = tt.s;
        }
        #pragma unroll
        for (int nfl = 0; nfl < 4; ++nfl) {
            int p = (wn * 4 + nfl) * 16 + (lane & 15);
            U4S8 tt;
            tt.u = *reinterpret_cast<const u32x4*>(&xs32[(32 + p) * 68 + kt * 16 + grp * 4]);
            #pragma unroll
            for (int mf = 0; mf < 4; ++mf)
                MFMA(acc[mf][nfl], ah[mf], tt.s);
        }
    }
    // states K-tile (kt = 4)
    {
        const uint32_t* stl32 = (const uint32_t*)stl;
        short8 ah[4];
        #pragma unroll
        for (int mf = 0; mf < 4; ++mf) {
            U4S8 tt;
            tt.u = *reinterpret_cast<const u32x4*>(&wsu[WCF + (32 + wm * 4 + mf) * 256 + lane * 4]);
            ah[mf] = tt.s;
        }
        #pragma unroll
        for (int nfl = 0; nfl < 4; ++nfl) {
            int p = (wn * 4 + nfl) * 16 + (lane & 15);
            U4S8 tt;
            tt.u = *reinterpret_cast<const u32x4*>(&stl32[p * 20 + grp * 4]);
            #pragma unroll
            for (int mf = 0; mf < 4; ++mf)
                MFMA(acc[mf][nfl], ah[mf], tt.s);
        }
    }

    // epilogue: + bias + residual (x re-read, L2-resident), nontemporal stores
    {
        const float* xb2 = xg + P0;
        int q4 = grp << 2;
        #pragma unroll
        for (int mf = 0; mf < 4; ++mf) {
            int cb2 = wm * 64 + mf * 16 + q4;
            f32x4 bc = *reinterpret_cast<const f32x4*>(ws + BIASC + cb2);
            #pragma unroll
            for (int j = 0; j < 4; ++j) {
                size_t rowa = (size_t)(cb2 + j) * LSEQ;
                #pragma unroll
                for (int nfl = 0; nfl < 4; ++nfl) {
                    int p = (wn * 4 + nfl) * 16 + (lane & 15);
                    float val = acc[mf][nfl][j] + bc[j] + xb2[rowa + p];
                    __builtin_nontemporal_store(val, &ob[rowa + p]);
                }
            }
        }
    }
}

// ---------------------------------------------------------------------------
extern "C" void kernel_launch(void* const* d_in, const int* in_sizes, int n_in,
                              void* d_out, int out_size, void* d_ws, size_t ws_size,
                              hipStream_t stream)
{
    const float* x     = (const float*)d_in[0];
    const float* A     = (const float*)d_in[1];
    const float* Bm    = (const float*)d_in[2];
    const float* Cm    = (const float*)d_in[3];
    const float* Dv    = (const float*)d_in[4];
    const float* W_in  = (const float*)d_in[5];
    const float* b_in  = (const float*)d_in[6];
    const float* W_out = (const float*)d_in[7];
    const float* b_out = (const float*)d_in[8];
    const float* gamma = (const float*)d_in[9];
    const float* beta  = (const float*)d_in[10];
    float* ws  = (float*)d_ws;
    float* out = (float*)d_out;

    prep_kernel <<<dim3(45),  dim3(256), 0, stream>>>(Bm, Cm, Dv, W_in, b_in, W_out, b_out, ws);
    fused_kernel<<<dim3(512), dim3(256), 0, stream>>>(x, A, gamma, beta, out, ws);
}